// Round 1
// baseline (3292.142 us; speedup 1.0000x reference)
//
#include <hip/hip_runtime.h>
#include <hip/hip_bf16.h>

#define DEV __device__ __forceinline__

typedef __attribute__((ext_vector_type(8))) __bf16 bfrag;   // 8 bf16 = 4 VGPRs (A/B frag)
typedef __attribute__((ext_vector_type(4))) float  f32x4;   // C/D frag

DEV f32x4 mfma32(bfrag a, bfrag b, f32x4 c) {
    return __builtin_amdgcn_mfma_f32_16x16x32_bf16(a, b, c, 0, 0, 0);
}

DEV unsigned short to_bf16(float f) {
    union { __bf16 b; unsigned short u; } cv;
    cv.b = (__bf16)f;
    return cv.u;
}

namespace cfg {
constexpr int B = 16384, P = 16, D = 49, H = 8, L = 6, FF = 196;
// workspace byte offsets (all 16B-aligned)
constexpr size_t OFF_ACC  = 0;                       // 128 floats (64 bins x {loss,acc})
constexpr size_t OFF_WQ   = 512;
constexpr size_t SZ_HEAD  = (size_t)L * H * 64 * 64 * 2;   // 393216
constexpr size_t OFF_WK   = OFF_WQ + SZ_HEAD;
constexpr size_t OFF_WV   = OFF_WK + SZ_HEAD;
constexpr size_t OFF_WH   = OFF_WV + SZ_HEAD;
constexpr size_t OFF_WO   = OFF_WH + SZ_HEAD;
constexpr size_t OFF_F1   = OFF_WO + SZ_HEAD;              // L*208*64 bf16
constexpr size_t OFF_F2   = OFF_F1 + (size_t)L * 208 * 64 * 2;  // L*64*224 bf16
constexpr size_t OFF_M1   = OFF_F2 + (size_t)L * 64 * 224 * 2;  // 64*64 bf16
constexpr size_t OFF_M2   = OFF_M1 + 8192;
constexpr size_t OFF_PP   = OFF_M2 + 8192;
constexpr size_t OFF_POSB = OFF_PP + 8192;                 // 16*64 f32 (pos + patch bias)
}

// ---------------- prepack kernels ----------------

__global__ void pack_heads(const float* __restrict__ wq, const float* __restrict__ wk,
                           const float* __restrict__ wv, const float* __restrict__ wh,
                           const float* __restrict__ wo, char* __restrict__ ws)
{
    int id = blockIdx.x * 256 + threadIdx.x;     // exactly 5*48*4096 threads
    int which = id / (48 * 4096);
    int rem   = id % (48 * 4096);
    int lh  = rem >> 12;
    int pos = rem & 4095;
    int n = pos >> 6, k = pos & 63;              // dst[n][k] = W_math[k][n]
    float v = 0.f;
    if (n < 49 && k < 49) {
        if (which < 4) {
            const float* s = (which == 0) ? wq : (which == 1) ? wk : (which == 2) ? wv : wh;
            v = s[((size_t)lh * 49 + k) * 49 + n];
        } else {
            int l = lh >> 3, h = lh & 7;
            v = wo[((size_t)l * 392 + h * 49 + k) * 49 + n];
        }
    }
    unsigned short* dst = (unsigned short*)(ws + cfg::OFF_WQ + (size_t)which * cfg::SZ_HEAD);
    dst[(size_t)lh * 4096 + pos] = to_bf16(v);
}

__global__ void pack_rest(const float* __restrict__ f1w, const float* __restrict__ f2w,
                          const float* __restrict__ m1w, const float* __restrict__ m2w,
                          const float* __restrict__ ppw, const float* __restrict__ ppb,
                          const float* __restrict__ pos, char* __restrict__ ws)
{
    int id = blockIdx.x * 256 + threadIdx.x;
    if (id < 6 * 208 * 64) {                                    // FFN1: [l][n=208][k=64]
        int l = id / (208 * 64), rem = id % (208 * 64), n = rem / 64, k = rem % 64;
        float v = (n < 196 && k < 49) ? f1w[((size_t)l * 49 + k) * 196 + n] : 0.f;
        ((unsigned short*)(ws + cfg::OFF_F1))[id] = to_bf16(v);
        return;
    }
    id -= 6 * 208 * 64;
    if (id < 6 * 64 * 224) {                                    // FFN2: [l][n=64][k=224]
        int l = id / (64 * 224), rem = id % (64 * 224), n = rem / 224, k = rem % 224;
        float v = (n < 49 && k < 196) ? f2w[((size_t)l * 196 + k) * 49 + n] : 0.f;
        ((unsigned short*)(ws + cfg::OFF_F2))[id] = to_bf16(v);
        return;
    }
    id -= 6 * 64 * 224;
    if (id < 4096) {
        int n = id >> 6, k = id & 63;
        ((unsigned short*)(ws + cfg::OFF_M1))[id] = to_bf16((n < 49 && k < 49) ? m1w[k * 49 + n] : 0.f);
        return;
    }
    id -= 4096;
    if (id < 4096) {
        int n = id >> 6, k = id & 63;
        ((unsigned short*)(ws + cfg::OFF_M2))[id] = to_bf16((n < 49 && k < 49) ? m2w[k * 49 + n] : 0.f);
        return;
    }
    id -= 4096;
    if (id < 4096) {
        int n = id >> 6, k = id & 63;
        ((unsigned short*)(ws + cfg::OFF_PP))[id] = to_bf16((n < 49 && k < 49) ? ppw[k * 49 + n] : 0.f);
        return;
    }
    id -= 4096;
    if (id < 1024) {                                            // posb[p][e] = pos + patch bias
        int p = id >> 6, e = id & 63;
        ((float*)(ws + cfg::OFF_POSB))[id] = (e < 49) ? pos[p * 49 + e] + ppb[e] : 0.f;
        return;
    }
    id -= 1024;
    if (id < 128) ((float*)(ws + cfg::OFF_ACC))[id] = 0.f;      // zero accumulator bins
}

// ---------------- main fused kernel: 1 wave per block, 2 elements per wave ----------------

__global__ __launch_bounds__(64)
void vit_main(const float* __restrict__ x, const int* __restrict__ trg,
              const float* __restrict__ bq, const float* __restrict__ bk_,
              const float* __restrict__ bv, const float* __restrict__ bh_,
              const float* __restrict__ bo,
              const float* __restrict__ ln1w, const float* __restrict__ ln1b,
              const float* __restrict__ ln2w, const float* __restrict__ ln2b,
              const float* __restrict__ f1bias, const float* __restrict__ f2bias,
              const float* __restrict__ m1b, const float* __restrict__ m2b,
              const float* __restrict__ cw1, const float* __restrict__ cb1,
              const float* __restrict__ cw2, const float* __restrict__ cb2,
              char* __restrict__ ws)
{
    // per-element LDS layout (ushort units): [16][64] tiles, row stride 64
    constexpr int EL = 6656;          // per-element footprint
    constexpr int HBF = 0;            // h (bf16)        [16][64]
    constexpr int S1  = 1024;         // Q / ao / y / hn [16][64]
    constexpr int S2  = 2048;         // K / ho / t      [16][64]
    constexpr int BIG = 3072;         // union: attention {VT,ATT} | FFN {MID}
    constexpr int VT  = BIG;          // V^T [64][32]  (e-major, token minor; tokens 16..31 zero)
    constexpr int ATT = BIG + 2048;   // P   [16][32]  (cols 16..31 zero)
    constexpr int MID = BIG;          // mid [16][224]

    __shared__ unsigned short sm[2 * EL];

    const int lane = threadIdx.x;
    const int g = lane >> 4;          // quad 0..3
    const int c = lane & 15;          // col-in-tile
    const long e0 = (long)blockIdx.x * 2;

    const unsigned short* WQ = (const unsigned short*)(ws + cfg::OFF_WQ);
    const unsigned short* WK = (const unsigned short*)(ws + cfg::OFF_WK);
    const unsigned short* WV = (const unsigned short*)(ws + cfg::OFF_WV);
    const unsigned short* WH = (const unsigned short*)(ws + cfg::OFF_WH);
    const unsigned short* WO = (const unsigned short*)(ws + cfg::OFF_WO);
    const unsigned short* F1 = (const unsigned short*)(ws + cfg::OFF_F1);
    const unsigned short* F2 = (const unsigned short*)(ws + cfg::OFF_F2);
    const unsigned short* M1 = (const unsigned short*)(ws + cfg::OFF_M1);
    const unsigned short* M2 = (const unsigned short*)(ws + cfg::OFF_M2);
    const unsigned short* PP = (const unsigned short*)(ws + cfg::OFF_PP);
    const float* POSB = (const float*)(ws + cfg::OFF_POSB);
    float* ACC = (float*)(ws + cfg::OFF_ACC);

    const f32x4 FZ = {0.f, 0.f, 0.f, 0.f};

    // ---- load x -> HBF (bf16, cols>=49 zeroed)
    for (int u = 0; u < 2; ++u) {
        const float* xb = x + (e0 + u) * (16 * 49);
        #pragma unroll
        for (int it = 0; it < 8; ++it) {
            int i = it * 64 + lane;            // 0..511 : 16 rows x 32 bf16-pairs
            int p = i >> 5, ee = (i & 31) * 2;
            float v0 = (ee < 49) ? xb[p * 49 + ee] : 0.f;
            float v1 = (ee + 1 < 49) ? xb[p * 49 + ee + 1] : 0.f;
            unsigned int pk = (unsigned)to_bf16(v0) | ((unsigned)to_bf16(v1) << 16);
            *reinterpret_cast<unsigned int*>(&sm[u * EL + HBF + p * 64 + ee]) = pk;
        }
    }
    __syncthreads();

    // A-fragment loader from a row-major [16][64] tile at offset `off`
    bfrag a_h[2][2];
    auto loadA = [&](int off, bfrag (&af)[2][2]) {
        #pragma unroll
        for (int u = 0; u < 2; ++u)
            #pragma unroll
            for (int kk = 0; kk < 2; ++kk)
                af[u][kk] = *(const bfrag*)&sm[u * EL + off + c * 64 + kk * 32 + g * 8];
    };

    // GEMM: dst = A(16x64) @ W(64x64) + bias, store bf16 (row-major or transposed-to-VT)
    auto proj_store = [&](bfrag (&af)[2][2], const unsigned short* w,
                          const float* bias, int bidx, int dst, bool transposed) {
        #pragma unroll
        for (int n = 0; n < 4; ++n) {
            f32x4 a0 = FZ, a1 = FZ;
            #pragma unroll
            for (int kk = 0; kk < 2; ++kk) {
                bfrag b = *(const bfrag*)&w[(n * 16 + c) * 64 + kk * 32 + g * 8];
                a0 = mfma32(af[0][kk], b, a0);
                a1 = mfma32(af[1][kk], b, a1);
            }
            int col = n * 16 + c;
            float bb = (col < 49) ? bias[bidx + col] : 0.f;
            #pragma unroll
            for (int r = 0; r < 4; ++r) {
                int row = 4 * g + r;
                unsigned short q0 = to_bf16(a0[r] + bb);
                unsigned short q1 = to_bf16(a1[r] + bb);
                if (!transposed) {
                    sm[0 * EL + dst + row * 64 + col] = q0;
                    sm[1 * EL + dst + row * 64 + col] = q1;
                } else {
                    sm[0 * EL + dst + col * 32 + row] = q0;   // VT[e][token]
                    sm[1 * EL + dst + col * 32 + row] = q1;
                }
            }
        }
    };

    // GEMM accumulate into register C (used for Wo head-concat accumulation)
    auto proj_acc = [&](bfrag (&af)[2][2], const unsigned short* w, f32x4 (&acc)[2][4]) {
        #pragma unroll
        for (int n = 0; n < 4; ++n)
            #pragma unroll
            for (int kk = 0; kk < 2; ++kk) {
                bfrag b = *(const bfrag*)&w[(n * 16 + c) * 64 + kk * 32 + g * 8];
                acc[0][n] = mfma32(af[0][kk], b, acc[0][n]);
                acc[1][n] = mfma32(af[1][kk], b, acc[1][n]);
            }
    };

    // ---- h0 = x @ patch_proj + (pos + patch_bias)
    loadA(HBF, a_h);
    f32x4 hreg[2][4];
    #pragma unroll
    for (int u = 0; u < 2; ++u)
        #pragma unroll
        for (int n = 0; n < 4; ++n) hreg[u][n] = FZ;
    #pragma unroll
    for (int n = 0; n < 4; ++n) {
        #pragma unroll
        for (int kk = 0; kk < 2; ++kk) {
            bfrag b = *(const bfrag*)&PP[(n * 16 + c) * 64 + kk * 32 + g * 8];
            hreg[0][n] = mfma32(a_h[0][kk], b, hreg[0][n]);
            hreg[1][n] = mfma32(a_h[1][kk], b, hreg[1][n]);
        }
        #pragma unroll
        for (int r = 0; r < 4; ++r) {
            float pb = POSB[(4 * g + r) * 64 + n * 16 + c];
            hreg[0][n][r] += pb;
            hreg[1][n][r] += pb;
        }
    }
    __syncthreads();

    // =================== layer loop ===================
    for (int l = 0; l < 6; ++l) {
        // write h (bf16) to HBF; zero token-padding of VT / ATT
        #pragma unroll
        for (int u = 0; u < 2; ++u)
            #pragma unroll
            for (int n = 0; n < 4; ++n)
                #pragma unroll
                for (int r = 0; r < 4; ++r)
                    sm[u * EL + HBF + (4 * g + r) * 64 + n * 16 + c] = to_bf16(hreg[u][n][r]);
        {
            bfrag bz;
            #pragma unroll
            for (int j = 0; j < 8; ++j) bz[j] = (__bf16)0.f;
            #pragma unroll
            for (int u = 0; u < 2; ++u) {
                *(bfrag*)&sm[u * EL + VT + lane * 32 + 16] = bz;
                *(bfrag*)&sm[u * EL + VT + lane * 32 + 24] = bz;
                if (lane < 16) {
                    *(bfrag*)&sm[u * EL + ATT + lane * 32 + 16] = bz;
                    *(bfrag*)&sm[u * EL + ATT + lane * 32 + 24] = bz;
                }
            }
        }
        __syncthreads();
        loadA(HBF, a_h);

        f32x4 oacc[2][4];
        #pragma unroll
        for (int u = 0; u < 2; ++u)
            #pragma unroll
            for (int n = 0; n < 4; ++n) oacc[u][n] = FZ;

        // ---------- attention heads ----------
        for (int hh = 0; hh < 8; ++hh) {
            const int lh = l * 8 + hh;
            proj_store(a_h, WQ + (size_t)lh * 4096, bq,  lh * 49, S1, false);
            proj_store(a_h, WK + (size_t)lh * 4096, bk_, lh * 49, S2, false);
            proj_store(a_h, WV + (size_t)lh * 4096, bv,  lh * 49, VT, true);
            __syncthreads();

            // scores = (Q K^T)/7, softmax over keys -> ATT (bf16)
            #pragma unroll
            for (int u = 0; u < 2; ++u) {
                f32x4 sc = FZ;
                #pragma unroll
                for (int kk = 0; kk < 2; ++kk) {
                    bfrag aq = *(const bfrag*)&sm[u * EL + S1 + c * 64 + kk * 32 + g * 8];
                    bfrag bk8 = *(const bfrag*)&sm[u * EL + S2 + c * 64 + kk * 32 + g * 8];
                    sc = mfma32(aq, bk8, sc);
                }
                #pragma unroll
                for (int r = 0; r < 4; ++r) {
                    float s = sc[r] * (1.f / 7.f);
                    float m = s;
                    m = fmaxf(m, __shfl_xor(m, 1));
                    m = fmaxf(m, __shfl_xor(m, 2));
                    m = fmaxf(m, __shfl_xor(m, 4));
                    m = fmaxf(m, __shfl_xor(m, 8));
                    float e = __expf(s - m);
                    float sum = e;
                    sum += __shfl_xor(sum, 1);
                    sum += __shfl_xor(sum, 2);
                    sum += __shfl_xor(sum, 4);
                    sum += __shfl_xor(sum, 8);
                    sm[u * EL + ATT + (4 * g + r) * 32 + c] = to_bf16(e / sum);
                }
            }
            __syncthreads();

            // ao = P @ V  -> S1 (row-major)
            {
                f32x4 ao[2][4];
                #pragma unroll
                for (int u = 0; u < 2; ++u) {
                    bfrag ap = *(const bfrag*)&sm[u * EL + ATT + c * 32 + g * 8];
                    #pragma unroll
                    for (int n = 0; n < 4; ++n) {
                        bfrag bv8 = *(const bfrag*)&sm[u * EL + VT + (n * 16 + c) * 32 + g * 8];
                        ao[u][n] = (n == 0 && false) ? FZ : ao[u][n]; // (init below)
                    }
                }
                #pragma unroll
                for (int u = 0; u < 2; ++u)
                    #pragma unroll
                    for (int n = 0; n < 4; ++n) ao[u][n] = FZ;
                #pragma unroll
                for (int u = 0; u < 2; ++u) {
                    bfrag ap = *(const bfrag*)&sm[u * EL + ATT + c * 32 + g * 8];
                    #pragma unroll
                    for (int n = 0; n < 4; ++n) {
                        bfrag bv8 = *(const bfrag*)&sm[u * EL + VT + (n * 16 + c) * 32 + g * 8];
                        ao[u][n] = mfma32(ap, bv8, ao[u][n]);
                    }
                }
                #pragma unroll
                for (int u = 0; u < 2; ++u)
                    #pragma unroll
                    for (int n = 0; n < 4; ++n)
                        #pragma unroll
                        for (int r = 0; r < 4; ++r)
                            sm[u * EL + S1 + (4 * g + r) * 64 + n * 16 + c] = to_bf16(ao[u][n][r]);
            }
            __syncthreads();

            // ho = ao @ Wh + bh -> S2
            bfrag aao[2][2];
            loadA(S1, aao);
            proj_store(aao, WH + (size_t)lh * 4096, bh_, lh * 49, S2, false);
            __syncthreads();

            // attn_out += ho @ Wo_blk (accumulated in registers across heads)
            bfrag aho[2][2];
            loadA(S2, aho);
            proj_acc(aho, WO + (size_t)lh * 4096, oacc);
            __syncthreads();
        }

        // ---------- LN1: y = LN(h + attn_out + bo) ----------
        f32x4 yreg[2][4];
        {
            float lw[4], lb[4];
            #pragma unroll
            for (int n = 0; n < 4; ++n) {
                int col = n * 16 + c;
                lw[n] = (col < 49) ? ln1w[l * 49 + col] : 0.f;
                lb[n] = (col < 49) ? ln1b[l * 49 + col] : 0.f;
            }
            #pragma unroll
            for (int u = 0; u < 2; ++u) {
                float z[4][4];
                #pragma unroll
                for (int n = 0; n < 4; ++n) {
                    int col = n * 16 + c;
                    float bov = (col < 49) ? bo[l * 49 + col] : 0.f;
                    #pragma unroll
                    for (int r = 0; r < 4; ++r)
                        z[n][r] = hreg[u][n][r] + oacc[u][n][r] + bov;
                }
                #pragma unroll
                for (int r = 0; r < 4; ++r) {
                    float s = z[0][r] + z[1][r] + z[2][r] + ((c == 0) ? z[3][r] : 0.f);
                    s += __shfl_xor(s, 1); s += __shfl_xor(s, 2);
                    s += __shfl_xor(s, 4); s += __shfl_xor(s, 8);
                    float mu = s * (1.f / 49.f);
                    float d0 = z[0][r] - mu, d1 = z[1][r] - mu, d2 = z[2][r] - mu;
                    float d3 = (c == 0) ? (z[3][r] - mu) : 0.f;
                    float v = d0 * d0 + d1 * d1 + d2 * d2 + d3 * d3;
                    v += __shfl_xor(v, 1); v += __shfl_xor(v, 2);
                    v += __shfl_xor(v, 4); v += __shfl_xor(v, 8);
                    float rstd = rsqrtf(v * (1.f / 49.f) + 1e-5f);
                    #pragma unroll
                    for (int n = 0; n < 4; ++n) {
                        int col = n * 16 + c;
                        float y = (col < 49) ? (z[n][r] - mu) * rstd * lw[n] + lb[n] : 0.f;
                        yreg[u][n][r] = y;
                        sm[u * EL + S1 + (4 * g + r) * 64 + col] = to_bf16(y);
                    }
                }
            }
        }
        __syncthreads();

        // ---------- FFN1: mid = gelu(y @ W1 + b1) -> MID [16][224] ----------
        {
            bfrag ay[2][2];
            loadA(S1, ay);
            const unsigned short* F1l = F1 + (size_t)l * 208 * 64;
            #pragma unroll
            for (int n = 0; n < 13; ++n) {
                f32x4 mm0 = FZ, mm1 = FZ;
                #pragma unroll
                for (int kk = 0; kk < 2; ++kk) {
                    bfrag b = *(const bfrag*)&F1l[(n * 16 + c) * 64 + kk * 32 + g * 8];
                    mm0 = mfma32(ay[0][kk], b, mm0);
                    mm1 = mfma32(ay[1][kk], b, mm1);
                }
                int col = n * 16 + c;
                float bb = (col < 196) ? f1bias[l * 196 + col] : 0.f;
                #pragma unroll
                for (int r = 0; r < 4; ++r) {
                    float v0 = mm0[r] + bb, v1 = mm1[r] + bb;
                    v0 = 0.5f * v0 * (1.f + erff(v0 * 0.70710678118f));
                    v1 = 0.5f * v1 * (1.f + erff(v1 * 0.70710678118f));
                    sm[0 * EL + MID + (4 * g + r) * 224 + col] = to_bf16(v0);
                    sm[1 * EL + MID + (4 * g + r) * 224 + col] = to_bf16(v1);
                }
            }
            // zero mid cols 208..223 (K-padding for FFN2)
            bfrag bz;
            #pragma unroll
            for (int j = 0; j < 8; ++j) bz[j] = (__bf16)0.f;
            int uu = lane >> 5, ii = lane & 31, row = ii >> 1, cc = 208 + (ii & 1) * 8;
            *(bfrag*)&sm[uu * EL + MID + row * 224 + cc] = bz;
        }
        __syncthreads();

        // ---------- FFN2 + residual + LN2 -> hreg; write hn -> S1 ----------
        {
            bfrag am[2][7];
            #pragma unroll
            for (int u = 0; u < 2; ++u)
                #pragma unroll
                for (int kk = 0; kk < 7; ++kk)
                    am[u][kk] = *(const bfrag*)&sm[u * EL + MID + c * 224 + kk * 32 + g * 8];
            const unsigned short* F2l = F2 + (size_t)l * 64 * 224;
            f32x4 zacc[2][4];
            #pragma unroll
            for (int n = 0; n < 4; ++n) {
                f32x4 t0 = FZ, t1 = FZ;
                #pragma unroll
                for (int kk = 0; kk < 7; ++kk) {
                    bfrag b = *(const bfrag*)&F2l[(n * 16 + c) * 224 + kk * 32 + g * 8];
                    t0 = mfma32(am[0][kk], b, t0);
                    t1 = mfma32(am[1][kk], b, t1);
                }
                zacc[0][n] = t0; zacc[1][n] = t1;
            }
            float lw[4], lb[4];
            #pragma unroll
            for (int n = 0; n < 4; ++n) {
                int col = n * 16 + c;
                lw[n] = (col < 49) ? ln2w[l * 49 + col] : 0.f;
                lb[n] = (col < 49) ? ln2b[l * 49 + col] : 0.f;
            }
            #pragma unroll
            for (int u = 0; u < 2; ++u) {
                float z[4][4];
                #pragma unroll
                for (int n = 0; n < 4; ++n) {
                    int col = n * 16 + c;
                    float fb = (col < 49) ? f2bias[l * 49 + col] : 0.f;
                    #pragma unroll
                    for (int r = 0; r < 4; ++r)
                        z[n][r] = yreg[u][n][r] + zacc[u][n][r] + fb;
                }
                #pragma unroll
                for (int r = 0; r < 4; ++r) {
                    float s = z[0][r] + z[1][r] + z[2][r] + ((c == 0) ? z[3][r] : 0.f);
                    s += __shfl_xor(s, 1); s += __shfl_xor(s, 2);
                    s += __shfl_xor(s, 4); s += __shfl_xor(s, 8);
                    float mu = s * (1.f / 49.f);
                    float d0 = z[0][r] - mu, d1 = z[1][r] - mu, d2 = z[2][r] - mu;
                    float d3 = (c == 0) ? (z[3][r] - mu) : 0.f;
                    float v = d0 * d0 + d1 * d1 + d2 * d2 + d3 * d3;
                    v += __shfl_xor(v, 1); v += __shfl_xor(v, 2);
                    v += __shfl_xor(v, 4); v += __shfl_xor(v, 8);
                    float rstd = rsqrtf(v * (1.f / 49.f) + 1e-5f);
                    #pragma unroll
                    for (int n = 0; n < 4; ++n) {
                        int col = n * 16 + c;
                        float hn = (col < 49) ? (z[n][r] - mu) * rstd * lw[n] + lb[n] : 0.f;
                        hreg[u][n][r] = hn;
                        sm[u * EL + S1 + (4 * g + r) * 64 + col] = to_bf16(hn);
                    }
                }
            }
        }
        __syncthreads();

        // ---------- inter-block MLP: h = (hn @ M1 + b1) @ M2 + b2 ----------
        {
            bfrag ahn[2][2];
            loadA(S1, ahn);
            proj_store(ahn, M1, m1b, 0, S2, false);
            __syncthreads();
            bfrag at[2][2];
            loadA(S2, at);
            #pragma unroll
            for (int n = 0; n < 4; ++n) {
                f32x4 t0 = FZ, t1 = FZ;
                #pragma unroll
                for (int kk = 0; kk < 2; ++kk) {
                    bfrag b = *(const bfrag*)&M2[(n * 16 + c) * 64 + kk * 32 + g * 8];
                    t0 = mfma32(at[0][kk], b, t0);
                    t1 = mfma32(at[1][kk], b, t1);
                }
                int col = n * 16 + c;
                float bb = (col < 49) ? m2b[col] : 0.f;
                #pragma unroll
                for (int r = 0; r < 4; ++r) {
                    hreg[0][n][r] = t0[r] + bb;
                    hreg[1][n][r] = t1[r] + bb;
                }
            }
        }
        __syncthreads();
    } // layers

    // =================== pooling + classifier + loss (fp32) ===================
    float loss_blk = 0.f, corr_blk = 0.f;
    for (int u = 0; u < 2; ++u) {
        float ps[4];
        #pragma unroll
        for (int n = 0; n < 4; ++n) {
            float s = hreg[u][n][0] + hreg[u][n][1] + hreg[u][n][2] + hreg[u][n][3];
            s += __shfl_xor(s, 16);
            s += __shfl_xor(s, 32);
            ps[n] = s * (1.f / 16.f);
        }
        float* pool = reinterpret_cast<float*>(&sm[u * EL + S1]);
        if (g == 0) {
            #pragma unroll
            for (int n = 0; n < 4; ++n) pool[n * 16 + c] = ps[n];
        }
        __syncthreads();
        float* l1v = pool + 64;
        if (lane < 25) {
            float s = cb1[lane];
            for (int d2 = 0; d2 < 49; ++d2) s += pool[d2] * cw1[d2 * 25 + lane];
            l1v[lane] = s;
        }
        __syncthreads();
        float* lg = l1v + 32;
        if (lane < 10) {
            float s = cb2[lane];
            for (int k2 = 0; k2 < 25; ++k2) s += l1v[k2] * cw2[k2 * 10 + lane];
            lg[lane] = s;
        }
        __syncthreads();
        if (lane == 0) {
            float m = lg[0]; int am_ = 0;
            for (int j = 1; j < 10; ++j) if (lg[j] > m) { m = lg[j]; am_ = j; }
            float se = 0.f;
            for (int j = 0; j < 10; ++j) se += __expf(lg[j] - m);
            float logZ = m + logf(se);
            int t = trg[e0 + u];
            loss_blk += logZ - lg[t];
            corr_blk += (am_ == t) ? 1.f : 0.f;
        }
        __syncthreads();
    }
    if (lane == 0) {
        int bin = blockIdx.x & 63;
        atomicAdd(&ACC[bin * 2 + 0], loss_blk);
        atomicAdd(&ACC[bin * 2 + 1], corr_blk);
    }
}

__global__ void finalize_k(const char* __restrict__ ws, float* __restrict__ out)
{
    const float* ACC = (const float*)(ws + cfg::OFF_ACC);
    int lane = threadIdx.x;
    float a = ACC[lane * 2 + 0];
    float b = ACC[lane * 2 + 1];
    for (int m = 1; m < 64; m <<= 1) {
        a += __shfl_xor(a, m);
        b += __shfl_xor(b, m);
    }
    if (lane == 0) {
        out[0] = a * (1.f / 16384.f);
        out[1] = b * (1.f / 16384.f);
    }
}

// ---------------- host launcher ----------------

extern "C" void kernel_launch(void* const* d_in, const int* in_sizes, int n_in,
                              void* d_out, int out_size, void* d_ws, size_t ws_size,
                              hipStream_t stream)
{
    const float* x    = (const float*)d_in[0];
    const int*   trg  = (const int*)  d_in[1];
    const float* ppw  = (const float*)d_in[2];
    const float* ppb  = (const float*)d_in[3];
    const float* pos  = (const float*)d_in[4];
    const float* wq   = (const float*)d_in[5];
    const float* bq   = (const float*)d_in[6];
    const float* wk   = (const float*)d_in[7];
    const float* bk   = (const float*)d_in[8];
    const float* wv   = (const float*)d_in[9];
    const float* bv   = (const float*)d_in[10];
    const float* wh   = (const float*)d_in[11];
    const float* bh   = (const float*)d_in[12];
    const float* wo   = (const float*)d_in[13];
    const float* bo   = (const float*)d_in[14];
    const float* ln1w = (const float*)d_in[15];
    const float* ln1b = (const float*)d_in[16];
    const float* ln2w = (const float*)d_in[17];
    const float* ln2b = (const float*)d_in[18];
    const float* f1w  = (const float*)d_in[19];
    const float* f1b  = (const float*)d_in[20];
    const float* f2w  = (const float*)d_in[21];
    const float* f2b  = (const float*)d_in[22];
    const float* m1w  = (const float*)d_in[23];
    const float* m1b  = (const float*)d_in[24];
    const float* m2w  = (const float*)d_in[25];
    const float* m2b  = (const float*)d_in[26];
    const float* cw1  = (const float*)d_in[27];
    const float* cb1  = (const float*)d_in[28];
    const float* cw2  = (const float*)d_in[29];
    const float* cb2  = (const float*)d_in[30];
    char* ws = (char*)d_ws;

    pack_heads<<<3840, 256, 0, stream>>>(wq, wk, wv, wh, wo, ws);
    pack_rest<<<701, 256, 0, stream>>>(f1w, f2w, m1w, m2w, ppw, ppb, pos, ws);
    vit_main<<<16384 / 2, 64, 0, stream>>>(x, trg, bq, bk, bv, bh, bo,
                                           ln1w, ln1b, ln2w, ln2b,
                                           f1b, f2b, m1b, m2b,
                                           cw1, cb1, cw2, cb2, ws);
    finalize_k<<<1, 64, 0, stream>>>(ws, (float*)d_out);
}

// Round 2
// 2664.968 us; speedup vs baseline: 1.2353x; 1.2353x over previous
//
#include <hip/hip_runtime.h>
#include <hip/hip_bf16.h>

#define DEV __device__ __forceinline__

typedef __attribute__((ext_vector_type(8))) __bf16 bfrag;   // 8 bf16 = 4 VGPRs (A/B frag)
typedef __attribute__((ext_vector_type(4))) float  f32x4;   // C/D frag

DEV f32x4 mfma32(bfrag a, bfrag b, f32x4 c) {
    return __builtin_amdgcn_mfma_f32_16x16x32_bf16(a, b, c, 0, 0, 0);
}

DEV unsigned short to_bf16(float f) {
    union { __bf16 b; unsigned short u; } cv;
    cv.b = (__bf16)f;
    return cv.u;
}

// pack 4 f32 -> 4 bf16 -> one ds_write_b64
DEV void store4(unsigned short* p, float v0, float v1, float v2, float v3) {
    unsigned long long q = (unsigned long long)to_bf16(v0)
        | ((unsigned long long)to_bf16(v1) << 16)
        | ((unsigned long long)to_bf16(v2) << 32)
        | ((unsigned long long)to_bf16(v3) << 48);
    *reinterpret_cast<unsigned long long*>(p) = q;
}

DEV float fastrcp(float x) { float r; asm("v_rcp_f32 %0, %1" : "=v"(r) : "v"(x)); return r; }

// exact-gelu via Abramowitz-Stegun 7.1.26 erf (|err| < 1.5e-7)
DEV float gelu(float v) {
    float ax = fabsf(v) * 0.70710678118f;
    float t = fastrcp(fmaf(0.3275911f, ax, 1.0f));
    float poly = t * fmaf(t, fmaf(t, fmaf(t, fmaf(t, 1.061405429f, -1.453152027f),
                                          1.421413741f), -0.284496736f), 0.254829592f);
    float er = 1.0f - poly * __expf(-ax * ax);
    er = copysignf(er, v);
    return 0.5f * v * (1.0f + er);
}

namespace cfg {
constexpr size_t OFF_ACC  = 0;                                  // 128 f32 bins
constexpr size_t OFF_WQ   = 512;
constexpr size_t SZ_HEAD  = (size_t)6 * 8 * 64 * 64 * 2;        // 393216
constexpr size_t OFF_WK   = OFF_WQ + SZ_HEAD;
constexpr size_t OFF_WV   = OFF_WK + SZ_HEAD;
constexpr size_t OFF_WH   = OFF_WV + SZ_HEAD;
constexpr size_t OFF_WO   = OFF_WH + SZ_HEAD;
constexpr size_t OFF_F1   = OFF_WO + SZ_HEAD;                   // 6*208*64 bf16
constexpr size_t OFF_F2   = OFF_F1 + (size_t)6 * 208 * 64 * 2;  // 6*64*224 bf16
constexpr size_t OFF_M1   = OFF_F2 + (size_t)6 * 64 * 224 * 2;
constexpr size_t OFF_M2   = OFF_M1 + 8192;
constexpr size_t OFF_PP   = OFF_M2 + 8192;
constexpr size_t OFF_POSB = OFF_PP + 8192;                      // 16*64 f32
constexpr size_t OFF_BQ   = OFF_POSB + 4096;                    // 48*64 f32 each
constexpr size_t OFF_BK   = OFF_BQ + 12288;
constexpr size_t OFF_BV   = OFF_BK + 12288;
constexpr size_t OFF_BH   = OFF_BV + 12288;
constexpr size_t OFF_BO   = OFF_BH + 12288;                     // 6*64 f32
constexpr size_t OFF_LN1W = OFF_BO + 1536;
constexpr size_t OFF_LN1B = OFF_LN1W + 1536;
constexpr size_t OFF_LN2W = OFF_LN1B + 1536;
constexpr size_t OFF_LN2B = OFF_LN2W + 1536;
constexpr size_t OFF_F1B  = OFF_LN2B + 1536;                    // 6*208 f32
constexpr size_t OFF_F2B  = OFF_F1B + 4992;                     // 6*64 f32
constexpr size_t OFF_M1B  = OFF_F2B + 1536;                     // 64 f32
constexpr size_t OFF_M2B  = OFF_M1B + 256;                      // 64 f32
}

// ---------------- prepack kernels ----------------

__global__ void pack_heads(const float* __restrict__ wq, const float* __restrict__ wk,
                           const float* __restrict__ wv, const float* __restrict__ wh,
                           const float* __restrict__ wo, char* __restrict__ ws)
{
    int id = blockIdx.x * 256 + threadIdx.x;     // exactly 5*48*4096 threads
    int which = id / (48 * 4096);
    int rem   = id % (48 * 4096);
    int lh  = rem >> 12;
    int pos = rem & 4095;
    int n = pos >> 6, k = pos & 63;              // dst[n][k] = W_math[k][n]
    float v = 0.f;
    if (n < 49 && k < 49) {
        if (which < 4) {
            const float* s = (which == 0) ? wq : (which == 1) ? wk : (which == 2) ? wv : wh;
            v = s[((size_t)lh * 49 + k) * 49 + n];
        } else {
            int l = lh >> 3, h = lh & 7;
            v = wo[((size_t)l * 392 + h * 49 + k) * 49 + n];
        }
    }
    unsigned short* dst = (unsigned short*)(ws + cfg::OFF_WQ + (size_t)which * cfg::SZ_HEAD);
    dst[(size_t)lh * 4096 + pos] = to_bf16(v);
}

__global__ void pack_rest(const float* __restrict__ f1w, const float* __restrict__ f2w,
                          const float* __restrict__ m1w, const float* __restrict__ m2w,
                          const float* __restrict__ ppw, const float* __restrict__ ppb,
                          const float* __restrict__ pos,
                          const float* __restrict__ bq, const float* __restrict__ bk,
                          const float* __restrict__ bv, const float* __restrict__ bh,
                          const float* __restrict__ bo,
                          const float* __restrict__ ln1w, const float* __restrict__ ln1b,
                          const float* __restrict__ ln2w, const float* __restrict__ ln2b,
                          const float* __restrict__ f1b, const float* __restrict__ f2b,
                          const float* __restrict__ m1b, const float* __restrict__ m2b,
                          char* __restrict__ ws)
{
    int id = blockIdx.x * 256 + threadIdx.x;
    if (id < 6 * 208 * 64) {                                    // FFN1: [l][n=208][k=64]
        int l = id / (208 * 64), rem = id % (208 * 64), n = rem / 64, k = rem % 64;
        float v = (n < 196 && k < 49) ? f1w[((size_t)l * 49 + k) * 196 + n] : 0.f;
        ((unsigned short*)(ws + cfg::OFF_F1))[id] = to_bf16(v);
        return;
    }
    id -= 6 * 208 * 64;
    if (id < 6 * 64 * 224) {                                    // FFN2: [l][n=64][k=224]
        int l = id / (64 * 224), rem = id % (64 * 224), n = rem / 224, k = rem % 224;
        float v = (n < 49 && k < 196) ? f2w[((size_t)l * 196 + k) * 49 + n] : 0.f;
        ((unsigned short*)(ws + cfg::OFF_F2))[id] = to_bf16(v);
        return;
    }
    id -= 6 * 64 * 224;
    if (id < 4096) {
        int n = id >> 6, k = id & 63;
        ((unsigned short*)(ws + cfg::OFF_M1))[id] = to_bf16((n < 49 && k < 49) ? m1w[k * 49 + n] : 0.f);
        return;
    }
    id -= 4096;
    if (id < 4096) {
        int n = id >> 6, k = id & 63;
        ((unsigned short*)(ws + cfg::OFF_M2))[id] = to_bf16((n < 49 && k < 49) ? m2w[k * 49 + n] : 0.f);
        return;
    }
    id -= 4096;
    if (id < 4096) {
        int n = id >> 6, k = id & 63;
        ((unsigned short*)(ws + cfg::OFF_PP))[id] = to_bf16((n < 49 && k < 49) ? ppw[k * 49 + n] : 0.f);
        return;
    }
    id -= 4096;
    if (id < 1024) {                                            // posb[p][e] = pos + patch bias
        int p = id >> 6, e = id & 63;
        ((float*)(ws + cfg::OFF_POSB))[id] = (e < 49) ? pos[p * 49 + e] + ppb[e] : 0.f;
        return;
    }
    id -= 1024;
    if (id < 128) { ((float*)(ws + cfg::OFF_ACC))[id] = 0.f; return; }
    id -= 128;
    if (id < 12288) {                                           // BQ/BK/BV/BH padded [48][64]
        int which = id / 3072, r = id % 3072, lh = r >> 6, f = r & 63;
        const float* s = (which == 0) ? bq : (which == 1) ? bk : (which == 2) ? bv : bh;
        float v = (f < 49) ? s[lh * 49 + f] : 0.f;
        ((float*)(ws + cfg::OFF_BQ + (size_t)which * 12288))[r] = v;
        return;
    }
    id -= 12288;
    if (id < 384) {                                             // BO [6][64]
        int l = id >> 6, f = id & 63;
        ((float*)(ws + cfg::OFF_BO))[id] = (f < 49) ? bo[l * 49 + f] : 0.f;
        return;
    }
    id -= 384;
    if (id < 1536) {                                            // LN params [6][64] x4
        int which = id / 384, r = id % 384, l = r >> 6, f = r & 63;
        const float* s = (which == 0) ? ln1w : (which == 1) ? ln1b : (which == 2) ? ln2w : ln2b;
        float v = (f < 49) ? s[l * 49 + f] : 0.f;
        ((float*)(ws + cfg::OFF_LN1W + (size_t)which * 1536))[r] = v;
        return;
    }
    id -= 1536;
    if (id < 1248) {                                            // F1B [6][208]
        int l = id / 208, f = id % 208;
        ((float*)(ws + cfg::OFF_F1B))[id] = (f < 196) ? f1b[l * 196 + f] : 0.f;
        return;
    }
    id -= 1248;
    if (id < 384) {                                             // F2B [6][64]
        int l = id >> 6, f = id & 63;
        ((float*)(ws + cfg::OFF_F2B))[id] = (f < 49) ? f2b[l * 49 + f] : 0.f;
        return;
    }
    id -= 384;
    if (id < 64) { ((float*)(ws + cfg::OFF_M1B))[id] = (id < 49) ? m1b[id] : 0.f; return; }
    id -= 64;
    if (id < 64) { ((float*)(ws + cfg::OFF_M2B))[id] = (id < 49) ? m2b[id] : 0.f; return; }
}

// ---------------- main fused kernel ----------------
// 1 wave/block, 2 elements/wave, transposed dataflow:
//   activations always [token][feature] (stride-padded), weights as A-operand,
//   C/D (row=feature,col=token) -> packed b64 stores. No __syncthreads needed
//   (single wave: DS ops are in-order).

__global__ __launch_bounds__(64, 2)
void vit_main(const float* __restrict__ x, const int* __restrict__ trg,
              const float* __restrict__ cw1, const float* __restrict__ cb1,
              const float* __restrict__ cw2, const float* __restrict__ cb2,
              char* __restrict__ ws)
{
    constexpr int S64 = 72;           // [16][64] tile row stride (ushorts): 144B, conflict-free
    constexpr int SV  = 40;           // VT [64 e][32 tok] stride: 80B
    constexpr int SP  = 40;           // P  [16 q][32 tok] stride
    constexpr int SM  = 232;          // MID [16][224] stride: 464B
    constexpr int TA = 0, TB = 1152, TC = 2304, TD = 4864, MIDO = 1152, EL = 5504;
    __shared__ unsigned short sm[2 * EL];   // 22016 B -> 7 blocks/CU

    const int lane = threadIdx.x;
    const int g = lane >> 4, c = lane & 15;
    const long e0 = (long)blockIdx.x * 2;
    const f32x4 FZ = {0.f, 0.f, 0.f, 0.f};

    const unsigned short* WQ = (const unsigned short*)(ws + cfg::OFF_WQ);
    const unsigned short* WK = (const unsigned short*)(ws + cfg::OFF_WK);
    const unsigned short* WV = (const unsigned short*)(ws + cfg::OFF_WV);
    const unsigned short* WH = (const unsigned short*)(ws + cfg::OFF_WH);
    const unsigned short* WO = (const unsigned short*)(ws + cfg::OFF_WO);
    const unsigned short* F1 = (const unsigned short*)(ws + cfg::OFF_F1);
    const unsigned short* F2 = (const unsigned short*)(ws + cfg::OFF_F2);
    const unsigned short* M1 = (const unsigned short*)(ws + cfg::OFF_M1);
    const unsigned short* M2 = (const unsigned short*)(ws + cfg::OFF_M2);
    const unsigned short* PP = (const unsigned short*)(ws + cfg::OFF_PP);
    const float* POSB = (const float*)(ws + cfg::OFF_POSB);
    const float* BQp  = (const float*)(ws + cfg::OFF_BQ);
    const float* BKp  = (const float*)(ws + cfg::OFF_BK);
    const float* BVp  = (const float*)(ws + cfg::OFF_BV);
    const float* BHp  = (const float*)(ws + cfg::OFF_BH);
    const float* BOp  = (const float*)(ws + cfg::OFF_BO);
    const float* LN1Wp = (const float*)(ws + cfg::OFF_LN1W);
    const float* LN1Bp = (const float*)(ws + cfg::OFF_LN1B);
    const float* LN2Wp = (const float*)(ws + cfg::OFF_LN2W);
    const float* LN2Bp = (const float*)(ws + cfg::OFF_LN2B);
    const float* F1Bp = (const float*)(ws + cfg::OFF_F1B);
    const float* F2Bp = (const float*)(ws + cfg::OFF_F2B);
    const float* M1Bp = (const float*)(ws + cfg::OFF_M1B);
    const float* M2Bp = (const float*)(ws + cfg::OFF_M2B);
    float* ACC = (float*)(ws + cfg::OFF_ACC);

    // ---- stage x -> TA ([tok][fin] bf16, fin>=49 zero)
    #pragma unroll
    for (int u = 0; u < 2; ++u) {
        const float* xb = x + (e0 + u) * 784;
        #pragma unroll
        for (int it = 0; it < 8; ++it) {
            int i = it * 64 + lane;
            int p = i >> 5, ee = (i & 31) * 2;
            float v0 = (ee < 49) ? xb[p * 49 + ee] : 0.f;
            float v1 = (ee + 1 < 49) ? xb[p * 49 + ee + 1] : 0.f;
            unsigned int pk = (unsigned)to_bf16(v0) | ((unsigned)to_bf16(v1) << 16);
            *reinterpret_cast<unsigned int*>(&sm[u * EL + TA + p * S64 + ee]) = pk;
        }
    }

    // B-fragment loader from a [16][64] tile (also serves as A-frag for row-major tiles)
    bfrag a_h[2][2];
    auto loadB = [&](int off, bfrag (&af)[2][2]) {
        #pragma unroll
        for (int u = 0; u < 2; ++u)
            #pragma unroll
            for (int kk = 0; kk < 2; ++kk)
                af[u][kk] = *(const bfrag*)&sm[u * EL + off + c * S64 + kk * 32 + g * 8];
    };
    loadB(TA, a_h);

    // ---- patch proj (transposed) + posb -> hreg  (lane: f=16m+4g+r, tok=c)
    f32x4 hreg[2][4];
    #pragma unroll
    for (int mt = 0; mt < 4; ++mt) {
        f32x4 t0 = FZ, t1 = FZ;
        #pragma unroll
        for (int kk = 0; kk < 2; ++kk) {
            bfrag w = *(const bfrag*)&PP[(mt * 16 + c) * 64 + kk * 32 + g * 8];
            t0 = mfma32(w, a_h[0][kk], t0);
            t1 = mfma32(w, a_h[1][kk], t1);
        }
        f32x4 pb = *(const f32x4*)&POSB[c * 64 + mt * 16 + 4 * g];
        hreg[0][mt] = t0 + pb;
        hreg[1][mt] = t1 + pb;
    }

    // =================== layer loop ===================
    for (int l = 0; l < 6; ++l) {
        // stage h -> TA
        #pragma unroll
        for (int u = 0; u < 2; ++u)
            #pragma unroll
            for (int mt = 0; mt < 4; ++mt)
                store4(&sm[u * EL + TA + c * S64 + mt * 16 + 4 * g],
                       hreg[u][mt][0], hreg[u][mt][1], hreg[u][mt][2], hreg[u][mt][3]);
        loadB(TA, a_h);

        // zero token-pad (16..31) of VT and P once per layer (MID overwrote them)
        #pragma unroll
        for (int u = 0; u < 2; ++u) {
            *(f32x4*)&sm[u * EL + TC + lane * SV + 16] = FZ;
            *(f32x4*)&sm[u * EL + TC + lane * SV + 24] = FZ;
        }
        {
            int u2 = lane >> 5, r5 = lane & 31, q = r5 >> 1, part = r5 & 1;
            *(f32x4*)&sm[u2 * EL + TD + q * SP + 16 + part * 8] = FZ;
        }

        f32x4 oacc[2][4];
        #pragma unroll
        for (int u = 0; u < 2; ++u)
            #pragma unroll
            for (int mt = 0; mt < 4; ++mt) oacc[u][mt] = FZ;

        // ---------- attention heads ----------
        for (int hh = 0; hh < 8; ++hh) {
            const int lh = l * 8 + hh;
            const unsigned short* wq = WQ + (size_t)lh * 4096;
            const unsigned short* wk = WK + (size_t)lh * 4096;
            const unsigned short* wv = WV + (size_t)lh * 4096;
            const unsigned short* wh = WH + (size_t)lh * 4096;
            const unsigned short* wo = WO + (size_t)lh * 4096;

            // Q -> TA, K -> TB (transposed projs)
            #pragma unroll
            for (int mt = 0; mt < 4; ++mt) {
                f32x4 q0 = FZ, q1 = FZ, k0 = FZ, k1 = FZ;
                #pragma unroll
                for (int kk = 0; kk < 2; ++kk) {
                    bfrag wqf = *(const bfrag*)&wq[(mt * 16 + c) * 64 + kk * 32 + g * 8];
                    bfrag wkf = *(const bfrag*)&wk[(mt * 16 + c) * 64 + kk * 32 + g * 8];
                    q0 = mfma32(wqf, a_h[0][kk], q0);
                    q1 = mfma32(wqf, a_h[1][kk], q1);
                    k0 = mfma32(wkf, a_h[0][kk], k0);
                    k1 = mfma32(wkf, a_h[1][kk], k1);
                }
                f32x4 bqv = *(const f32x4*)&BQp[lh * 64 + mt * 16 + 4 * g];
                f32x4 bkv = *(const f32x4*)&BKp[lh * 64 + mt * 16 + 4 * g];
                store4(&sm[0 * EL + TA + c * S64 + mt * 16 + 4 * g],
                       q0[0] + bqv[0], q0[1] + bqv[1], q0[2] + bqv[2], q0[3] + bqv[3]);
                store4(&sm[1 * EL + TA + c * S64 + mt * 16 + 4 * g],
                       q1[0] + bqv[0], q1[1] + bqv[1], q1[2] + bqv[2], q1[3] + bqv[3]);
                store4(&sm[0 * EL + TB + c * S64 + mt * 16 + 4 * g],
                       k0[0] + bkv[0], k0[1] + bkv[1], k0[2] + bkv[2], k0[3] + bkv[3]);
                store4(&sm[1 * EL + TB + c * S64 + mt * 16 + 4 * g],
                       k1[0] + bkv[0], k1[1] + bkv[1], k1[2] + bkv[2], k1[3] + bkv[3]);
            }
            // V (normal orientation) -> VT [e][tok]
            #pragma unroll
            for (int nt = 0; nt < 4; ++nt) {
                f32x4 v0 = FZ, v1 = FZ;
                #pragma unroll
                for (int kk = 0; kk < 2; ++kk) {
                    bfrag wvf = *(const bfrag*)&wv[(nt * 16 + c) * 64 + kk * 32 + g * 8];
                    v0 = mfma32(a_h[0][kk], wvf, v0);
                    v1 = mfma32(a_h[1][kk], wvf, v1);
                }
                float bvv = BVp[lh * 64 + nt * 16 + c];
                store4(&sm[0 * EL + TC + (nt * 16 + c) * SV + 4 * g],
                       v0[0] + bvv, v0[1] + bvv, v0[2] + bvv, v0[3] + bvv);
                store4(&sm[1 * EL + TC + (nt * 16 + c) * SV + 4 * g],
                       v1[0] + bvv, v1[1] + bvv, v1[2] + bvv, v1[3] + bvv);
            }

            // S^T = K·Q^T (lane: k_tok=4g+r, q=c), softmax over k -> P[q][k] in TD
            #pragma unroll
            for (int u = 0; u < 2; ++u) {
                f32x4 sc = FZ;
                #pragma unroll
                for (int kk = 0; kk < 2; ++kk) {
                    bfrag akf = *(const bfrag*)&sm[u * EL + TB + c * S64 + kk * 32 + g * 8];
                    bfrag aqf = *(const bfrag*)&sm[u * EL + TA + c * S64 + kk * 32 + g * 8];
                    sc = mfma32(akf, aqf, sc);
                }
                float s0 = sc[0] * (1.f / 7.f), s1 = sc[1] * (1.f / 7.f);
                float s2 = sc[2] * (1.f / 7.f), s3 = sc[3] * (1.f / 7.f);
                float m = fmaxf(fmaxf(s0, s1), fmaxf(s2, s3));
                m = fmaxf(m, __shfl_xor(m, 16));
                m = fmaxf(m, __shfl_xor(m, 32));
                float p0 = __expf(s0 - m), p1 = __expf(s1 - m);
                float p2 = __expf(s2 - m), p3 = __expf(s3 - m);
                float t = p0 + p1 + p2 + p3;
                t += __shfl_xor(t, 16);
                t += __shfl_xor(t, 32);
                float inv = fastrcp(t);
                store4(&sm[u * EL + TD + c * SP + 4 * g], p0 * inv, p1 * inv, p2 * inv, p3 * inv);
            }

            // ao^T = V^T·P^T (K=32, token pad zeroed) -> ao[q][e] in TA (Q dead)
            #pragma unroll
            for (int u = 0; u < 2; ++u) {
                bfrag bp = *(const bfrag*)&sm[u * EL + TD + c * SP + g * 8];
                #pragma unroll
                for (int mt = 0; mt < 4; ++mt) {
                    bfrag av = *(const bfrag*)&sm[u * EL + TC + (mt * 16 + c) * SV + g * 8];
                    f32x4 o = mfma32(av, bp, FZ);
                    store4(&sm[u * EL + TA + c * S64 + mt * 16 + 4 * g], o[0], o[1], o[2], o[3]);
                }
            }

            // ho^T = Wh^T·ao^T -> TB (K dead)
            bfrag aa[2][2];
            loadB(TA, aa);
            #pragma unroll
            for (int mt = 0; mt < 4; ++mt) {
                f32x4 h0 = FZ, h1 = FZ;
                #pragma unroll
                for (int kk = 0; kk < 2; ++kk) {
                    bfrag wf = *(const bfrag*)&wh[(mt * 16 + c) * 64 + kk * 32 + g * 8];
                    h0 = mfma32(wf, aa[0][kk], h0);
                    h1 = mfma32(wf, aa[1][kk], h1);
                }
                f32x4 bhv = *(const f32x4*)&BHp[lh * 64 + mt * 16 + 4 * g];
                store4(&sm[0 * EL + TB + c * S64 + mt * 16 + 4 * g],
                       h0[0] + bhv[0], h0[1] + bhv[1], h0[2] + bhv[2], h0[3] + bhv[3]);
                store4(&sm[1 * EL + TB + c * S64 + mt * 16 + 4 * g],
                       h1[0] + bhv[0], h1[1] + bhv[1], h1[2] + bhv[2], h1[3] + bhv[3]);
            }

            // oacc^T += Wo_blk^T·ho^T (register accumulate)
            bfrag ab[2][2];
            loadB(TB, ab);
            #pragma unroll
            for (int mt = 0; mt < 4; ++mt)
                #pragma unroll
                for (int kk = 0; kk < 2; ++kk) {
                    bfrag wf = *(const bfrag*)&wo[(mt * 16 + c) * 64 + kk * 32 + g * 8];
                    oacc[0][mt] = mfma32(wf, ab[0][kk], oacc[0][mt]);
                    oacc[1][mt] = mfma32(wf, ab[1][kk], oacc[1][mt]);
                }
        } // heads

        // ---------- LN1: y = LN(h + attn_out + bo) -> yreg, store y -> TA ----------
        f32x4 yreg[2][4];
        #pragma unroll
        for (int u = 0; u < 2; ++u) {
            float z[4][4];
            float s = 0.f, q2 = 0.f;
            #pragma unroll
            for (int mt = 0; mt < 4; ++mt) {
                f32x4 bov = *(const f32x4*)&BOp[l * 64 + mt * 16 + 4 * g];
                #pragma unroll
                for (int r = 0; r < 4; ++r) {
                    float zz = hreg[u][mt][r] + oacc[u][mt][r] + bov[r];
                    z[mt][r] = zz;
                    s += zz;
                    q2 += zz * zz;
                }
            }
            s += __shfl_xor(s, 16); s += __shfl_xor(s, 32);
            q2 += __shfl_xor(q2, 16); q2 += __shfl_xor(q2, 32);
            float mu = s * (1.f / 49.f);
            float var = q2 * (1.f / 49.f) - mu * mu;
            float rstd = rsqrtf(var + 1e-5f);
            #pragma unroll
            for (int mt = 0; mt < 4; ++mt) {
                f32x4 lwv = *(const f32x4*)&LN1Wp[l * 64 + mt * 16 + 4 * g];
                f32x4 lbv = *(const f32x4*)&LN1Bp[l * 64 + mt * 16 + 4 * g];
                #pragma unroll
                for (int r = 0; r < 4; ++r)
                    yreg[u][mt][r] = (z[mt][r] - mu) * rstd * lwv[r] + lbv[r];
                store4(&sm[u * EL + TA + c * S64 + mt * 16 + 4 * g],
                       yreg[u][mt][0], yreg[u][mt][1], yreg[u][mt][2], yreg[u][mt][3]);
            }
        }

        // ---------- FFN1: mid = gelu(y W1 + b1) -> MID [tok][224] ----------
        {
            bfrag ay[2][2];
            loadB(TA, ay);
            // zero MID cols 208..223 (K-pad for FFN2)
            int u2 = lane >> 5, r5 = lane & 31, row = r5 >> 1, half = r5 & 1;
            *(f32x4*)&sm[u2 * EL + MIDO + row * SM + 208 + half * 8] = FZ;

            const unsigned short* F1l = F1 + (size_t)l * 208 * 64;
            const float* f1bp = F1Bp + l * 208;
            #pragma unroll
            for (int mt = 0; mt < 13; ++mt) {
                f32x4 m0 = FZ, m1 = FZ;
                #pragma unroll
                for (int kk = 0; kk < 2; ++kk) {
                    bfrag wf = *(const bfrag*)&F1l[(mt * 16 + c) * 64 + kk * 32 + g * 8];
                    m0 = mfma32(wf, ay[0][kk], m0);
                    m1 = mfma32(wf, ay[1][kk], m1);
                }
                f32x4 bb = *(const f32x4*)&f1bp[mt * 16 + 4 * g];
                store4(&sm[0 * EL + MIDO + c * SM + mt * 16 + 4 * g],
                       gelu(m0[0] + bb[0]), gelu(m0[1] + bb[1]),
                       gelu(m0[2] + bb[2]), gelu(m0[3] + bb[3]));
                store4(&sm[1 * EL + MIDO + c * SM + mt * 16 + 4 * g],
                       gelu(m1[0] + bb[0]), gelu(m1[1] + bb[1]),
                       gelu(m1[2] + bb[2]), gelu(m1[3] + bb[3]));
            }
        }

        // ---------- FFN2 + residual + LN2 -> hreg (hn), store hn -> TA ----------
        {
            bfrag am[2][7];
            #pragma unroll
            for (int u = 0; u < 2; ++u)
                #pragma unroll
                for (int kk = 0; kk < 7; ++kk)
                    am[u][kk] = *(const bfrag*)&sm[u * EL + MIDO + c * SM + kk * 32 + g * 8];
            const unsigned short* F2l = F2 + (size_t)l * 64 * 224;
            f32x4 zac[2][4];
            #pragma unroll
            for (int mt = 0; mt < 4; ++mt) {
                f32x4 t0 = FZ, t1 = FZ;
                #pragma unroll
                for (int kk = 0; kk < 7; ++kk) {
                    bfrag wf = *(const bfrag*)&F2l[(mt * 16 + c) * 224 + kk * 32 + g * 8];
                    t0 = mfma32(wf, am[0][kk], t0);
                    t1 = mfma32(wf, am[1][kk], t1);
                }
                zac[0][mt] = t0; zac[1][mt] = t1;
            }
            #pragma unroll
            for (int u = 0; u < 2; ++u) {
                float z[4][4];
                float s = 0.f, q2 = 0.f;
                #pragma unroll
                for (int mt = 0; mt < 4; ++mt) {
                    f32x4 fbv = *(const f32x4*)&F2Bp[l * 64 + mt * 16 + 4 * g];
                    #pragma unroll
                    for (int r = 0; r < 4; ++r) {
                        float zz = yreg[u][mt][r] + zac[u][mt][r] + fbv[r];
                        z[mt][r] = zz;
                        s += zz;
                        q2 += zz * zz;
                    }
                }
                s += __shfl_xor(s, 16); s += __shfl_xor(s, 32);
                q2 += __shfl_xor(q2, 16); q2 += __shfl_xor(q2, 32);
                float mu = s * (1.f / 49.f);
                float var = q2 * (1.f / 49.f) - mu * mu;
                float rstd = rsqrtf(var + 1e-5f);
                #pragma unroll
                for (int mt = 0; mt < 4; ++mt) {
                    f32x4 lwv = *(const f32x4*)&LN2Wp[l * 64 + mt * 16 + 4 * g];
                    f32x4 lbv = *(const f32x4*)&LN2Bp[l * 64 + mt * 16 + 4 * g];
                    #pragma unroll
                    for (int r = 0; r < 4; ++r)
                        hreg[u][mt][r] = (z[mt][r] - mu) * rstd * lwv[r] + lbv[r];
                    store4(&sm[u * EL + TA + c * S64 + mt * 16 + 4 * g],
                           hreg[u][mt][0], hreg[u][mt][1], hreg[u][mt][2], hreg[u][mt][3]);
                }
            }
        }

        // ---------- inter-block MLP ----------
        {
            bfrag an[2][2];
            loadB(TA, an);
            #pragma unroll
            for (int mt = 0; mt < 4; ++mt) {
                f32x4 t0 = FZ, t1 = FZ;
                #pragma unroll
                for (int kk = 0; kk < 2; ++kk) {
                    bfrag wf = *(const bfrag*)&M1[(mt * 16 + c) * 64 + kk * 32 + g * 8];
                    t0 = mfma32(wf, an[0][kk], t0);
                    t1 = mfma32(wf, an[1][kk], t1);
                }
                f32x4 bb = *(const f32x4*)&M1Bp[mt * 16 + 4 * g];
                store4(&sm[0 * EL + TB + c * S64 + mt * 16 + 4 * g],
                       t0[0] + bb[0], t0[1] + bb[1], t0[2] + bb[2], t0[3] + bb[3]);
                store4(&sm[1 * EL + TB + c * S64 + mt * 16 + 4 * g],
                       t1[0] + bb[0], t1[1] + bb[1], t1[2] + bb[2], t1[3] + bb[3]);
            }
            bfrag at2[2][2];
            loadB(TB, at2);
            #pragma unroll
            for (int mt = 0; mt < 4; ++mt) {
                f32x4 t0 = FZ, t1 = FZ;
                #pragma unroll
                for (int kk = 0; kk < 2; ++kk) {
                    bfrag wf = *(const bfrag*)&M2[(mt * 16 + c) * 64 + kk * 32 + g * 8];
                    t0 = mfma32(wf, at2[0][kk], t0);
                    t1 = mfma32(wf, at2[1][kk], t1);
                }
                f32x4 bb = *(const f32x4*)&M2Bp[mt * 16 + 4 * g];
                hreg[0][mt] = t0 + bb;
                hreg[1][mt] = t1 + bb;
            }
        }
    } // layers

    // =================== pooling + classifier + loss (fp32) ===================
    float loss_blk = 0.f, corr_blk = 0.f;
    #pragma unroll
    for (int u = 0; u < 2; ++u)
        #pragma unroll
        for (int mt = 0; mt < 4; ++mt)
            store4(&sm[u * EL + TA + c * S64 + mt * 16 + 4 * g],
                   hreg[u][mt][0], hreg[u][mt][1], hreg[u][mt][2], hreg[u][mt][3]);

    for (int u = 0; u < 2; ++u) {
        // each lane sums its feature column f=lane over 16 tokens
        float s = 0.f;
        #pragma unroll
        for (int p = 0; p < 16; ++p)
            s += (float)(*reinterpret_cast<const __bf16*>(&sm[u * EL + TA + p * S64 + lane]));
        float* pf = reinterpret_cast<float*>(&sm[u * EL + TC]);
        pf[lane] = s * (1.f / 16.f);
        if (lane < 25) {
            float t = cb1[lane];
            for (int d2 = 0; d2 < 49; ++d2) t += pf[d2] * cw1[d2 * 25 + lane];
            pf[64 + lane] = t;
        }
        if (lane < 10) {
            float t2 = cb2[lane];
            for (int k2 = 0; k2 < 25; ++k2) t2 += pf[64 + k2] * cw2[k2 * 10 + lane];
            pf[96 + lane] = t2;
        }
        if (lane == 0) {
            float m = pf[96]; int am_ = 0;
            for (int j = 1; j < 10; ++j) if (pf[96 + j] > m) { m = pf[96 + j]; am_ = j; }
            float se = 0.f;
            for (int j = 0; j < 10; ++j) se += __expf(pf[96 + j] - m);
            float logZ = m + logf(se);
            int t = trg[e0 + u];
            loss_blk += logZ - pf[96 + t];
            corr_blk += (am_ == t) ? 1.f : 0.f;
        }
    }
    if (lane == 0) {
        int bin = blockIdx.x & 63;
        atomicAdd(&ACC[bin * 2 + 0], loss_blk);
        atomicAdd(&ACC[bin * 2 + 1], corr_blk);
    }
}

__global__ void finalize_k(const char* __restrict__ ws, float* __restrict__ out)
{
    const float* ACC = (const float*)(ws + cfg::OFF_ACC);
    int lane = threadIdx.x;
    float a = ACC[lane * 2 + 0];
    float b = ACC[lane * 2 + 1];
    for (int m = 1; m < 64; m <<= 1) {
        a += __shfl_xor(a, m);
        b += __shfl_xor(b, m);
    }
    if (lane == 0) {
        out[0] = a * (1.f / 16384.f);
        out[1] = b * (1.f / 16384.f);
    }
}

// ---------------- host launcher ----------------

extern "C" void kernel_launch(void* const* d_in, const int* in_sizes, int n_in,
                              void* d_out, int out_size, void* d_ws, size_t ws_size,
                              hipStream_t stream)
{
    const float* x    = (const float*)d_in[0];
    const int*   trg  = (const int*)  d_in[1];
    const float* ppw  = (const float*)d_in[2];
    const float* ppb  = (const float*)d_in[3];
    const float* pos  = (const float*)d_in[4];
    const float* wq   = (const float*)d_in[5];
    const float* bq   = (const float*)d_in[6];
    const float* wk   = (const float*)d_in[7];
    const float* bk   = (const float*)d_in[8];
    const float* wv   = (const float*)d_in[9];
    const float* bv   = (const float*)d_in[10];
    const float* wh   = (const float*)d_in[11];
    const float* bh   = (const float*)d_in[12];
    const float* wo   = (const float*)d_in[13];
    const float* bo   = (const float*)d_in[14];
    const float* ln1w = (const float*)d_in[15];
    const float* ln1b = (const float*)d_in[16];
    const float* ln2w = (const float*)d_in[17];
    const float* ln2b = (const float*)d_in[18];
    const float* f1w  = (const float*)d_in[19];
    const float* f1b  = (const float*)d_in[20];
    const float* f2w  = (const float*)d_in[21];
    const float* f2b  = (const float*)d_in[22];
    const float* m1w  = (const float*)d_in[23];
    const float* m1b  = (const float*)d_in[24];
    const float* m2w  = (const float*)d_in[25];
    const float* m2b  = (const float*)d_in[26];
    const float* cw1  = (const float*)d_in[27];
    const float* cb1  = (const float*)d_in[28];
    const float* cw2  = (const float*)d_in[29];
    const float* cb2  = (const float*)d_in[30];
    char* ws = (char*)d_ws;

    pack_heads<<<3840, 256, 0, stream>>>(wq, wk, wv, wh, wo, ws);
    pack_rest<<<763, 256, 0, stream>>>(f1w, f2w, m1w, m2w, ppw, ppb, pos,
                                       bq, bk, bv, bh, bo,
                                       ln1w, ln1b, ln2w, ln2b,
                                       f1b, f2b, m1b, m2b, ws);
    vit_main<<<16384 / 2, 64, 0, stream>>>(x, trg, cw1, cb1, cw2, cb2, ws);
    finalize_k<<<1, 64, 0, stream>>>(ws, (float*)d_out);
}

// Round 3
// 1808.915 us; speedup vs baseline: 1.8200x; 1.4732x over previous
//
#include <hip/hip_runtime.h>
#include <hip/hip_bf16.h>

#define DEV __device__ __forceinline__

typedef __attribute__((ext_vector_type(8))) __bf16 bfrag;   // 8 bf16 = 4 VGPRs (A/B frag)
typedef __attribute__((ext_vector_type(4))) float  f32x4;   // C/D frag

DEV f32x4 mfma32(bfrag a, bfrag b, f32x4 c) {
    return __builtin_amdgcn_mfma_f32_16x16x32_bf16(a, b, c, 0, 0, 0);
}

DEV unsigned short to_bf16(float f) {
    union { __bf16 b; unsigned short u; } cv;
    cv.b = (__bf16)f;
    return cv.u;
}

#if defined(__has_builtin)
#if __has_builtin(__builtin_amdgcn_cvt_pk_bf16_f32)
#define HAS_PK_BF16 1
#endif
#endif

DEV unsigned int pk2(float a, float b) {
#ifdef HAS_PK_BF16
    auto r = __builtin_amdgcn_cvt_pk_bf16_f32(a, b);
    unsigned int u;
    __builtin_memcpy(&u, &r, 4);
    return u;
#else
    return (unsigned)to_bf16(a) | ((unsigned)to_bf16(b) << 16);
#endif
}

// pack 4 f32 -> 4 bf16 -> one 8B LDS store
DEV void store4(unsigned short* p, float v0, float v1, float v2, float v3) {
    typedef __attribute__((ext_vector_type(2))) unsigned int uint2v;
    uint2v q;
    q[0] = pk2(v0, v1);
    q[1] = pk2(v2, v3);
    *reinterpret_cast<uint2v*>(p) = q;
}

DEV float fastrcp(float x) { float r; asm("v_rcp_f32 %0, %1" : "=v"(r) : "v"(x)); return r; }

// tanh-form gelu via sigmoid: x*sigmoid(1.5957691x + 0.07135481x^3), |err|<~1.5e-3
DEV float gelu(float x) {
    float u = x * fmaf(0.07135481f, x * x, 1.5957691f);
    float e = __expf(-u);
    return x * fastrcp(1.0f + e);
}

namespace cfg {
constexpr size_t OFF_ACC  = 0;                                  // 128 f32 bins
constexpr size_t OFF_WQ   = 512;
constexpr size_t SZ_HEAD  = (size_t)48 * 64 * 64 * 2;           // 393216
constexpr size_t OFF_WK   = OFF_WQ + SZ_HEAD;
constexpr size_t OFF_WV   = OFF_WK + SZ_HEAD;
constexpr size_t OFF_WHOO = OFF_WV + SZ_HEAD;                   // fused Wh@Wo per head
constexpr size_t OFF_F1   = OFF_WHOO + SZ_HEAD;                 // 6*208*64 bf16
constexpr size_t OFF_F2   = OFF_F1 + (size_t)6 * 208 * 64 * 2;  // 6*64*224 bf16
constexpr size_t OFF_MF   = OFF_F2 + (size_t)6 * 64 * 224 * 2;  // fused M1@M2 [64][64]
constexpr size_t OFF_PP   = OFF_MF + 8192;
constexpr size_t OFF_POSB = OFF_PP + 8192;                      // 16*64 f32 (pos + patch bias)
}

// ---------------- prepack kernels ----------------

// Q/K/V weights packed [out 64][in 64], in-slot 49 = bias (consumed by constant-1 activation slot)
__global__ void pack_qkv(const float* __restrict__ wq, const float* __restrict__ bq,
                         const float* __restrict__ wk, const float* __restrict__ bk,
                         const float* __restrict__ wv, const float* __restrict__ bv,
                         char* __restrict__ ws)
{
    int id = blockIdx.x * 256 + threadIdx.x;     // 3*48*4096 threads
    int which = id / (48 * 4096);
    int rem   = id % (48 * 4096);
    int lh  = rem >> 12;
    int pos = rem & 4095;
    int n = pos >> 6, k = pos & 63;              // n = out feature, k = in feature
    const float* w = (which == 0) ? wq : (which == 1) ? wk : wv;
    const float* b = (which == 0) ? bq : (which == 1) ? bk : bv;
    float v = 0.f;
    if (n < 49) {
        if (k < 49)       v = w[((size_t)lh * 49 + k) * 49 + n];
        else if (k == 49) v = b[lh * 49 + n];
    }
    unsigned short* dst = (unsigned short*)(ws + cfg::OFF_WQ + (size_t)which * cfg::SZ_HEAD);
    dst[(size_t)lh * 4096 + pos] = to_bf16(v);
}

// fused Whoo[lh][d out][e in] = sum_o Wh[lh][e][o]*Wo[l][h*49+o][d]; slot e=49 = bh@Wo + bo/8
// fused Mf[d out][e in] = sum_o M1[e][o]*M2[o][d]; slot e=49 = b1@M2 + b2
__global__ void pack_fused(const float* __restrict__ wh, const float* __restrict__ bh,
                           const float* __restrict__ wo, const float* __restrict__ bo,
                           const float* __restrict__ m1, const float* __restrict__ m1b,
                           const float* __restrict__ m2, const float* __restrict__ m2b,
                           char* __restrict__ ws)
{
    int id = blockIdx.x * 256 + threadIdx.x;     // 48*4096 + 4096 threads
    if (id < 48 * 4096) {
        int lh = id >> 12, pos = id & 4095;
        int l = lh >> 3, h = lh & 7;
        int d = pos >> 6, e = pos & 63;
        float s = 0.f;
        if (d < 49) {
            if (e < 49) {
                for (int o = 0; o < 49; ++o)
                    s += wh[((size_t)lh * 49 + e) * 49 + o] * wo[((size_t)l * 392 + h * 49 + o) * 49 + d];
            } else if (e == 49) {
                for (int o = 0; o < 49; ++o)
                    s += bh[lh * 49 + o] * wo[((size_t)l * 392 + h * 49 + o) * 49 + d];
                s += bo[l * 49 + d] * 0.125f;
            }
        }
        ((unsigned short*)(ws + cfg::OFF_WHOO))[(size_t)lh * 4096 + d * 64 + e] = to_bf16(s);
        return;
    }
    id -= 48 * 4096;
    if (id < 4096) {
        int d = id >> 6, e = id & 63;
        float s = 0.f;
        if (d < 49) {
            if (e < 49) {
                for (int o = 0; o < 49; ++o) s += m1[e * 49 + o] * m2[o * 49 + d];
            } else if (e == 49) {
                for (int o = 0; o < 49; ++o) s += m1b[o] * m2[o * 49 + d];
                s += m2b[d];
            }
        }
        ((unsigned short*)(ws + cfg::OFF_MF))[d * 64 + e] = to_bf16(s);
    }
}

__global__ void pack_rest(const float* __restrict__ f1w, const float* __restrict__ f1b,
                          const float* __restrict__ f2w, const float* __restrict__ f2b,
                          const float* __restrict__ ppw, const float* __restrict__ ppb,
                          const float* __restrict__ pos, char* __restrict__ ws)
{
    int id = blockIdx.x * 256 + threadIdx.x;
    if (id < 6 * 208 * 64) {                                    // FFN1: [l][n=208][k=64], k-slot49=bias
        int l = id / (208 * 64), rem = id % (208 * 64), n = rem / 64, k = rem % 64;
        float v = 0.f;
        if (n < 196) {
            if (k < 49)       v = f1w[((size_t)l * 49 + k) * 196 + n];
            else if (k == 49) v = f1b[l * 196 + n];
        }
        ((unsigned short*)(ws + cfg::OFF_F1))[id] = to_bf16(v);
        return;
    }
    id -= 6 * 208 * 64;
    if (id < 6 * 64 * 224) {                                    // FFN2: [l][n=64][k=224], k-slot196=bias
        int l = id / (64 * 224), rem = id % (64 * 224), n = rem / 224, k = rem % 224;
        float v = 0.f;
        if (n < 49) {
            if (k < 196)       v = f2w[((size_t)l * 196 + k) * 49 + n];
            else if (k == 196) v = f2b[l * 49 + n];
        }
        ((unsigned short*)(ws + cfg::OFF_F2))[id] = to_bf16(v);
        return;
    }
    id -= 6 * 64 * 224;
    if (id < 4096) {                                            // patch proj [n][k] (bias via POSB)
        int n = id >> 6, k = id & 63;
        ((unsigned short*)(ws + cfg::OFF_PP))[id] = to_bf16((n < 49 && k < 49) ? ppw[k * 49 + n] : 0.f);
        return;
    }
    id -= 4096;
    if (id < 1024) {                                            // posb[p][e] = pos + patch bias
        int p = id >> 6, e = id & 63;
        ((float*)(ws + cfg::OFF_POSB))[id] = (e < 49) ? pos[p * 49 + e] + ppb[e] : 0.f;
        return;
    }
    id -= 1024;
    if (id < 128) ((float*)(ws + cfg::OFF_ACC))[id] = 0.f;      // zero accumulator bins
}

// ---------------- main fused kernel ----------------
// 1 wave/block, 2 elements/wave, transposed dataflow, all biases folded into
// weight K-slot 49 (constant-1 activation slot). No __syncthreads (single wave).

__global__ __launch_bounds__(64, 2)
void vit_main(const float* __restrict__ x, const int* __restrict__ trg,
              const float* __restrict__ cw1, const float* __restrict__ cb1,
              const float* __restrict__ cw2, const float* __restrict__ cb2,
              char* __restrict__ ws)
{
    constexpr int S64 = 72;           // [16][64] tile stride (ushorts), 144B
    constexpr int SV  = 40;           // VT [52 e][32 tok] stride, 80B
    constexpr int SP  = 40;           // P  [16 q][32 tok] stride
    constexpr int SM  = 232;          // MID [16][224] stride, 464B
    constexpr int TA = 0, TB = 1152, TV = 2304, TP = 4384, MIDO = 1152, EL = 5024;
    __shared__ unsigned short sm[2 * EL];   // 20096 B -> 8 blocks/CU (exactly 160KB)

    const int lane = threadIdx.x;
    const int g = lane >> 4, c = lane & 15;
    const long e0 = (long)blockIdx.x * 2;
    const f32x4 FZ = {0.f, 0.f, 0.f, 0.f};

    const unsigned short* WQ = (const unsigned short*)(ws + cfg::OFF_WQ);
    const unsigned short* WK = (const unsigned short*)(ws + cfg::OFF_WK);
    const unsigned short* WV = (const unsigned short*)(ws + cfg::OFF_WV);
    const unsigned short* WHOO = (const unsigned short*)(ws + cfg::OFF_WHOO);
    const unsigned short* F1 = (const unsigned short*)(ws + cfg::OFF_F1);
    const unsigned short* F2 = (const unsigned short*)(ws + cfg::OFF_F2);
    const unsigned short* MF = (const unsigned short*)(ws + cfg::OFF_MF);
    const unsigned short* PP = (const unsigned short*)(ws + cfg::OFF_PP);
    const float* POSB = (const float*)(ws + cfg::OFF_POSB);
    float* ACC = (float*)(ws + cfg::OFF_ACC);

    // ---- stage x -> TA ([tok][feat] bf16, feats>=49 zero)
    #pragma unroll
    for (int u = 0; u < 2; ++u) {
        const float* xb = x + (e0 + u) * 784;
        #pragma unroll
        for (int it = 0; it < 8; ++it) {
            int i = it * 64 + lane;
            int p = i >> 5, ee = (i & 31) * 2;
            float v0 = (ee < 49) ? xb[p * 49 + ee] : 0.f;
            float v1 = (ee + 1 < 49) ? xb[p * 49 + ee + 1] : 0.f;
            *reinterpret_cast<unsigned int*>(&sm[u * EL + TA + p * S64 + ee]) = pk2(v0, v1);
        }
    }
    // once: zero P rows 12..15 cols 16..39 (outside MID overlay; survive all layers)
    if (lane < 24) {
        int u2 = lane / 12, r = lane % 12, row = 12 + r / 3, seg = r % 3;
        *(f32x4*)&sm[u2 * EL + TP + row * SP + 16 + seg * 8] = FZ;
    }

    // B-fragment loader from a [16][64] tile (rows = n/tok, cols = k contiguous)
    bfrag a_h[2][2];
    auto loadB = [&](int off, bfrag (&af)[2][2]) {
        #pragma unroll
        for (int u = 0; u < 2; ++u)
            #pragma unroll
            for (int kk = 0; kk < 2; ++kk)
                af[u][kk] = *(const bfrag*)&sm[u * EL + off + c * S64 + kk * 32 + g * 8];
    };
    loadB(TA, a_h);

    // ---- patch proj (transposed) + posb -> hreg  (lane: f=16mt+4g+r, tok=c)
    f32x4 hreg[2][4];
    #pragma unroll
    for (int mt = 0; mt < 4; ++mt) {
        f32x4 t0 = FZ, t1 = FZ;
        #pragma unroll
        for (int kk = 0; kk < 2; ++kk) {
            bfrag w = *(const bfrag*)&PP[(mt * 16 + c) * 64 + kk * 32 + g * 8];
            t0 = mfma32(w, a_h[0][kk], t0);
            t1 = mfma32(w, a_h[1][kk], t1);
        }
        f32x4 pb = *(const f32x4*)&POSB[c * 64 + mt * 16 + 4 * g];
        hreg[0][mt] = t0 + pb;
        hreg[1][mt] = t1 + pb;
    }

    // =================== layer loop ===================
    for (int l = 0; l < 6; ++l) {
        // stage h -> TA, set constant-1 slot at feat 49
        #pragma unroll
        for (int u = 0; u < 2; ++u)
            #pragma unroll
            for (int mt = 0; mt < 4; ++mt)
                store4(&sm[u * EL + TA + c * S64 + mt * 16 + 4 * g],
                       hreg[u][mt][0], hreg[u][mt][1], hreg[u][mt][2], hreg[u][mt][3]);
        if (lane < 32) sm[(lane >> 4) * EL + TA + (lane & 15) * S64 + 49] = 0x3F80;
        loadB(TA, a_h);

        // zero token-pad cols 16..31 of VT rows 0..63 (rows 52..63 land in P rows 0..11)
        #pragma unroll
        for (int u = 0; u < 2; ++u) {
            *(f32x4*)&sm[u * EL + TV + lane * SV + 16] = FZ;
            *(f32x4*)&sm[u * EL + TV + lane * SV + 24] = FZ;
        }

        f32x4 oacc[2][4];
        #pragma unroll
        for (int u = 0; u < 2; ++u)
            #pragma unroll
            for (int mt = 0; mt < 4; ++mt) oacc[u][mt] = FZ;

        // ---------- attention heads ----------
        for (int hh = 0; hh < 8; ++hh) {
            const int lh = l * 8 + hh;
            const unsigned short* wq = WQ + (size_t)lh * 4096;
            const unsigned short* wk = WK + (size_t)lh * 4096;
            const unsigned short* wv = WV + (size_t)lh * 4096;
            const unsigned short* who = WHOO + (size_t)lh * 4096;

            // Q -> TA, K -> TB (transposed projs; bias via slot)
            #pragma unroll
            for (int mt = 0; mt < 4; ++mt) {
                f32x4 q0 = FZ, q1 = FZ, k0 = FZ, k1 = FZ;
                #pragma unroll
                for (int kk = 0; kk < 2; ++kk) {
                    bfrag wqf = *(const bfrag*)&wq[(mt * 16 + c) * 64 + kk * 32 + g * 8];
                    bfrag wkf = *(const bfrag*)&wk[(mt * 16 + c) * 64 + kk * 32 + g * 8];
                    q0 = mfma32(wqf, a_h[0][kk], q0);
                    q1 = mfma32(wqf, a_h[1][kk], q1);
                    k0 = mfma32(wkf, a_h[0][kk], k0);
                    k1 = mfma32(wkf, a_h[1][kk], k1);
                }
                store4(&sm[0 * EL + TA + c * S64 + mt * 16 + 4 * g], q0[0], q0[1], q0[2], q0[3]);
                store4(&sm[1 * EL + TA + c * S64 + mt * 16 + 4 * g], q1[0], q1[1], q1[2], q1[3]);
                store4(&sm[0 * EL + TB + c * S64 + mt * 16 + 4 * g], k0[0], k0[1], k0[2], k0[3]);
                store4(&sm[1 * EL + TB + c * S64 + mt * 16 + 4 * g], k1[0], k1[1], k1[2], k1[3]);
            }
            // V (normal orientation) -> VT [e][tok]  (rows 52..63 spill into P rows 0..11
            // as zeros; overwritten by the softmax P stores before PV reads them)
            #pragma unroll
            for (int nt = 0; nt < 4; ++nt) {
                f32x4 v0 = FZ, v1 = FZ;
                #pragma unroll
                for (int kk = 0; kk < 2; ++kk) {
                    bfrag wvf = *(const bfrag*)&wv[(nt * 16 + c) * 64 + kk * 32 + g * 8];
                    v0 = mfma32(a_h[0][kk], wvf, v0);
                    v1 = mfma32(a_h[1][kk], wvf, v1);
                }
                store4(&sm[0 * EL + TV + (nt * 16 + c) * SV + 4 * g], v0[0], v0[1], v0[2], v0[3]);
                store4(&sm[1 * EL + TV + (nt * 16 + c) * SV + 4 * g], v1[0], v1[1], v1[2], v1[3]);
            }

            // S^T = K·Q^T (lane: k_tok=4g+r, q=c), softmax over k -> P[q][k] in TP
            #pragma unroll
            for (int u = 0; u < 2; ++u) {
                f32x4 sc = FZ;
                #pragma unroll
                for (int kk = 0; kk < 2; ++kk) {
                    bfrag akf = *(const bfrag*)&sm[u * EL + TB + c * S64 + kk * 32 + g * 8];
                    bfrag aqf = *(const bfrag*)&sm[u * EL + TA + c * S64 + kk * 32 + g * 8];
                    sc = mfma32(akf, aqf, sc);
                }
                float s0 = sc[0] * (1.f / 7.f), s1 = sc[1] * (1.f / 7.f);
                float s2 = sc[2] * (1.f / 7.f), s3 = sc[3] * (1.f / 7.f);
                float m = fmaxf(fmaxf(s0, s1), fmaxf(s2, s3));
                m = fmaxf(m, __shfl_xor(m, 16));
                m = fmaxf(m, __shfl_xor(m, 32));
                float p0 = __expf(s0 - m), p1 = __expf(s1 - m);
                float p2 = __expf(s2 - m), p3 = __expf(s3 - m);
                float t = p0 + p1 + p2 + p3;
                t += __shfl_xor(t, 16);
                t += __shfl_xor(t, 32);
                float inv = fastrcp(t);
                store4(&sm[u * EL + TP + c * SP + 4 * g], p0 * inv, p1 * inv, p2 * inv, p3 * inv);
            }

            // ao^T = V^T·P^T -> ao[q][e] in TA (Q dead); set slot e=49 to 1
            #pragma unroll
            for (int u = 0; u < 2; ++u) {
                bfrag bp = *(const bfrag*)&sm[u * EL + TP + c * SP + g * 8];
                #pragma unroll
                for (int mt = 0; mt < 4; ++mt) {
                    bfrag av = *(const bfrag*)&sm[u * EL + TV + (mt * 16 + c) * SV + g * 8];
                    f32x4 o = mfma32(av, bp, FZ);
                    store4(&sm[u * EL + TA + c * S64 + mt * 16 + 4 * g], o[0], o[1], o[2], o[3]);
                }
            }
            if (lane < 32) sm[(lane >> 4) * EL + TA + (lane & 15) * S64 + 49] = 0x3F80;

            // oacc += Whoo^T·ao^T  (fused Wh@Wo, bias in slot, register accumulate)
            bfrag ab[2][2];
            loadB(TA, ab);
            #pragma unroll
            for (int mt = 0; mt < 4; ++mt)
                #pragma unroll
                for (int kk = 0; kk < 2; ++kk) {
                    bfrag wf = *(const bfrag*)&who[(mt * 16 + c) * 64 + kk * 32 + g * 8];
                    oacc[0][mt] = mfma32(wf, ab[0][kk], oacc[0][mt]);
                    oacc[1][mt] = mfma32(wf, ab[1][kk], oacc[1][mt]);
                }
        } // heads

        // ---------- LN1: y = LN(h + attn_out) -> yreg, store y -> TA (+slot) ----------
        f32x4 yreg[2][4];
        #pragma unroll
        for (int u = 0; u < 2; ++u) {
            float z[4][4];
            float s = 0.f, q2 = 0.f;
            #pragma unroll
            for (int mt = 0; mt < 4; ++mt)
                #pragma unroll
                for (int r = 0; r < 4; ++r) {
                    float zz = hreg[u][mt][r] + oacc[u][mt][r];
                    z[mt][r] = zz;
                    s += zz;
                    q2 += zz * zz;
                }
            s += __shfl_xor(s, 16); s += __shfl_xor(s, 32);
            q2 += __shfl_xor(q2, 16); q2 += __shfl_xor(q2, 32);
            float mu = s * (1.f / 49.f);
            float var = q2 * (1.f / 49.f) - mu * mu;
            float rstd = rsqrtf(var + 1e-5f);
            const float* lw = (const float*)(ws + cfg::OFF_POSB);  // placeholder reuse? no:
            (void)lw;
            #pragma unroll
            for (int mt = 0; mt < 4; ++mt) {
                // ln1 w/b loaded below via globals
                (void)0;
                f32x4 dummy; (void)dummy;
                break;
            }
            // apply gamma/beta
            #pragma unroll
            for (int mt = 0; mt < 4; ++mt) {
                #pragma unroll
                for (int r = 0; r < 4; ++r)
                    yreg[u][mt][r] = (z[mt][r] - mu) * rstd;
                // gamma/beta applied after (see below) — but we need them here:
            }
        }
        // NOTE: gamma/beta for LN are NOT folded (y is also the residual). Load and apply.
        {
            extern __shared__ unsigned short _smdummy[]; (void)_smdummy;
        }
        // re-apply with ln1 params (ws tables were removed; use original inputs passed via cw-style? )
        // --- see lnparams below ---
        {
            const float* ln1wp = (const float*)(ws + cfg::OFF_POSB + 4096);  // LN tables appended
            const float* ln1bp = ln1wp + 384;
            #pragma unroll
            for (int u = 0; u < 2; ++u)
                #pragma unroll
                for (int mt = 0; mt < 4; ++mt) {
                    f32x4 lwv = *(const f32x4*)&ln1wp[l * 64 + mt * 16 + 4 * g];
                    f32x4 lbv = *(const f32x4*)&ln1bp[l * 64 + mt * 16 + 4 * g];
                    #pragma unroll
                    for (int r = 0; r < 4; ++r)
                        yreg[u][mt][r] = yreg[u][mt][r] * lwv[r] + lbv[r];
                    store4(&sm[u * EL + TA + c * S64 + mt * 16 + 4 * g],
                           yreg[u][mt][0], yreg[u][mt][1], yreg[u][mt][2], yreg[u][mt][3]);
                }
        }
        if (lane < 32) sm[(lane >> 4) * EL + TA + (lane & 15) * S64 + 49] = 0x3F80;

        // ---------- FFN1: mid = gelu(y W1 + b1) -> MID [tok][224] ----------
        {
            bfrag ay[2][2];
            loadB(TA, ay);
            // zero MID cols 208..223 (K-pad for FFN2)
            {
                int u2 = lane >> 5, r5 = lane & 31, row = r5 >> 1, half = r5 & 1;
                *(f32x4*)&sm[u2 * EL + MIDO + row * SM + 208 + half * 8] = FZ;
            }
            const unsigned short* F1l = F1 + (size_t)l * 208 * 64;
            #pragma unroll
            for (int mt = 0; mt < 13; ++mt) {
                f32x4 m0 = FZ, m1 = FZ;
                #pragma unroll
                for (int kk = 0; kk < 2; ++kk) {
                    bfrag wf = *(const bfrag*)&F1l[(mt * 16 + c) * 64 + kk * 32 + g * 8];
                    m0 = mfma32(wf, ay[0][kk], m0);
                    m1 = mfma32(wf, ay[1][kk], m1);
                }
                store4(&sm[0 * EL + MIDO + c * SM + mt * 16 + 4 * g],
                       gelu(m0[0]), gelu(m0[1]), gelu(m0[2]), gelu(m0[3]));
                store4(&sm[1 * EL + MIDO + c * SM + mt * 16 + 4 * g],
                       gelu(m1[0]), gelu(m1[1]), gelu(m1[2]), gelu(m1[3]));
            }
            // constant-1 slot at mid col 196 (consumes f2 bias row)
            if (lane < 32) sm[(lane >> 4) * EL + MIDO + (lane & 15) * SM + 196] = 0x3F80;
        }

        // ---------- FFN2 + residual + LN2 -> hreg (hn), store hn -> TA (+slot) ----------
        {
            bfrag am[2][7];
            #pragma unroll
            for (int u = 0; u < 2; ++u)
                #pragma unroll
                for (int kk = 0; kk < 7; ++kk)
                    am[u][kk] = *(const bfrag*)&sm[u * EL + MIDO + c * SM + kk * 32 + g * 8];
            const unsigned short* F2l = F2 + (size_t)l * 64 * 224;
            f32x4 zac[2][4];
            #pragma unroll
            for (int mt = 0; mt < 4; ++mt) {
                f32x4 t0 = FZ, t1 = FZ;
                #pragma unroll
                for (int kk = 0; kk < 7; ++kk) {
                    bfrag wf = *(const bfrag*)&F2l[(mt * 16 + c) * 224 + kk * 32 + g * 8];
                    t0 = mfma32(wf, am[0][kk], t0);
                    t1 = mfma32(wf, am[1][kk], t1);
                }
                zac[0][mt] = t0; zac[1][mt] = t1;
            }
            const float* ln2wp = (const float*)(ws + cfg::OFF_POSB + 4096) + 768;
            const float* ln2bp = ln2wp + 384;
            #pragma unroll
            for (int u = 0; u < 2; ++u) {
                float z[4][4];
                float s = 0.f, q2 = 0.f;
                #pragma unroll
                for (int mt = 0; mt < 4; ++mt)
                    #pragma unroll
                    for (int r = 0; r < 4; ++r) {
                        float zz = yreg[u][mt][r] + zac[u][mt][r];
                        z[mt][r] = zz;
                        s += zz;
                        q2 += zz * zz;
                    }
                s += __shfl_xor(s, 16); s += __shfl_xor(s, 32);
                q2 += __shfl_xor(q2, 16); q2 += __shfl_xor(q2, 32);
                float mu = s * (1.f / 49.f);
                float var = q2 * (1.f / 49.f) - mu * mu;
                float rstd = rsqrtf(var + 1e-5f);
                #pragma unroll
                for (int mt = 0; mt < 4; ++mt) {
                    f32x4 lwv = *(const f32x4*)&ln2wp[l * 64 + mt * 16 + 4 * g];
                    f32x4 lbv = *(const f32x4*)&ln2bp[l * 64 + mt * 16 + 4 * g];
                    #pragma unroll
                    for (int r = 0; r < 4; ++r)
                        hreg[u][mt][r] = (z[mt][r] - mu) * rstd * lwv[r] + lbv[r];
                    store4(&sm[u * EL + TA + c * S64 + mt * 16 + 4 * g],
                           hreg[u][mt][0], hreg[u][mt][1], hreg[u][mt][2], hreg[u][mt][3]);
                }
            }
        }
        if (lane < 32) sm[(lane >> 4) * EL + TA + (lane & 15) * S64 + 49] = 0x3F80;

        // ---------- inter-block MLP (fused M1@M2, bias in slot) ----------
        {
            bfrag an[2][2];
            loadB(TA, an);
            #pragma unroll
            for (int mt = 0; mt < 4; ++mt) {
                f32x4 t0 = FZ, t1 = FZ;
                #pragma unroll
                for (int kk = 0; kk < 2; ++kk) {
                    bfrag wf = *(const bfrag*)&MF[(mt * 16 + c) * 64 + kk * 32 + g * 8];
                    t0 = mfma32(wf, an[0][kk], t0);
                    t1 = mfma32(wf, an[1][kk], t1);
                }
                hreg[0][mt] = t0;
                hreg[1][mt] = t1;
            }
        }
    } // layers

    // =================== pooling + classifier + loss (fp32) ===================
    float loss_blk = 0.f, corr_blk = 0.f;
    #pragma unroll
    for (int u = 0; u < 2; ++u)
        #pragma unroll
        for (int mt = 0; mt < 4; ++mt)
            store4(&sm[u * EL + TA + c * S64 + mt * 16 + 4 * g],
                   hreg[u][mt][0], hreg[u][mt][1], hreg[u][mt][2], hreg[u][mt][3]);

    for (int u = 0; u < 2; ++u) {
        float s = 0.f;
        #pragma unroll
        for (int p = 0; p < 16; ++p)
            s += (float)(*reinterpret_cast<const __bf16*>(&sm[u * EL + TA + p * S64 + lane]));
        float* pf = reinterpret_cast<float*>(&sm[u * EL + TV]);
        pf[lane] = s * (1.f / 16.f);
        if (lane < 25) {
            float t = cb1[lane];
            for (int d2 = 0; d2 < 49; ++d2) t += pf[d2] * cw1[d2 * 25 + lane];
            pf[64 + lane] = t;
        }
        if (lane < 10) {
            float t2 = cb2[lane];
            for (int k2 = 0; k2 < 25; ++k2) t2 += pf[64 + k2] * cw2[k2 * 10 + lane];
            pf[96 + lane] = t2;
        }
        if (lane == 0) {
            float m = pf[96]; int am_ = 0;
            for (int j = 1; j < 10; ++j) if (pf[96 + j] > m) { m = pf[96 + j]; am_ = j; }
            float se = 0.f;
            for (int j = 0; j < 10; ++j) se += __expf(pf[96 + j] - m);
            float logZ = m + logf(se);
            int t = trg[e0 + u];
            loss_blk += logZ - pf[96 + t];
            corr_blk += (am_ == t) ? 1.f : 0.f;
        }
    }
    if (lane == 0) {
        int bin = blockIdx.x & 63;
        atomicAdd(&ACC[bin * 2 + 0], loss_blk);
        atomicAdd(&ACC[bin * 2 + 1], corr_blk);
    }
}

// pack LN params [6][64] x4 (w1,b1,w2,b2) after POSB
__global__ void pack_ln(const float* __restrict__ ln1w, const float* __restrict__ ln1b,
                        const float* __restrict__ ln2w, const float* __restrict__ ln2b,
                        char* __restrict__ ws)
{
    int id = blockIdx.x * 256 + threadIdx.x;     // 1536 threads
    if (id >= 1536) return;
    int which = id / 384, r = id % 384, l = r >> 6, f = r & 63;
    const float* s = (which == 0) ? ln1w : (which == 1) ? ln1b : (which == 2) ? ln2w : ln2b;
    float v = (f < 49) ? s[l * 49 + f] : 0.f;
    ((float*)(ws + cfg::OFF_POSB + 4096))[which * 384 + r] = v;
}

__global__ void finalize_k(const char* __restrict__ ws, float* __restrict__ out)
{
    const float* ACC = (const float*)(ws + cfg::OFF_ACC);
    int lane = threadIdx.x;
    float a = ACC[lane * 2 + 0];
    float b = ACC[lane * 2 + 1];
    for (int m = 1; m < 64; m <<= 1) {
        a += __shfl_xor(a, m);
        b += __shfl_xor(b, m);
    }
    if (lane == 0) {
        out[0] = a * (1.f / 16384.f);
        out[1] = b * (1.f / 16384.f);
    }
}

// ---------------- host launcher ----------------

extern "C" void kernel_launch(void* const* d_in, const int* in_sizes, int n_in,
                              void* d_out, int out_size, void* d_ws, size_t ws_size,
                              hipStream_t stream)
{
    const float* x    = (const float*)d_in[0];
    const int*   trg  = (const int*)  d_in[1];
    const float* ppw  = (const float*)d_in[2];
    const float* ppb  = (const float*)d_in[3];
    const float* pos  = (const float*)d_in[4];
    const float* wq   = (const float*)d_in[5];
    const float* bq   = (const float*)d_in[6];
    const float* wk   = (const float*)d_in[7];
    const float* bk   = (const float*)d_in[8];
    const float* wv   = (const float*)d_in[9];
    const float* bv   = (const float*)d_in[10];
    const float* wh   = (const float*)d_in[11];
    const float* bh   = (const float*)d_in[12];
    const float* wo   = (const float*)d_in[13];
    const float* bo   = (const float*)d_in[14];
    const float* ln1w = (const float*)d_in[15];
    const float* ln1b = (const float*)d_in[16];
    const float* ln2w = (const float*)d_in[17];
    const float* ln2b = (const float*)d_in[18];
    const float* f1w  = (const float*)d_in[19];
    const float* f1b  = (const float*)d_in[20];
    const float* f2w  = (const float*)d_in[21];
    const float* f2b  = (const float*)d_in[22];
    const float* m1w  = (const float*)d_in[23];
    const float* m1b  = (const float*)d_in[24];
    const float* m2w  = (const float*)d_in[25];
    const float* m2b  = (const float*)d_in[26];
    const float* cw1  = (const float*)d_in[27];
    const float* cb1  = (const float*)d_in[28];
    const float* cw2  = (const float*)d_in[29];
    const float* cb2  = (const float*)d_in[30];
    char* ws = (char*)d_ws;

    pack_qkv<<<2304, 256, 0, stream>>>(wq, bq, wk, bk, wv, bv, ws);
    pack_fused<<<784, 256, 0, stream>>>(wh, bh, wo, bo, m1w, m1b, m2w, m2b, ws);
    pack_rest<<<669, 256, 0, stream>>>(f1w, f1b, f2w, f2b, ppw, ppb, pos, ws);
    pack_ln<<<6, 256, 0, stream>>>(ln1w, ln1b, ln2w, ln2b, ws);
    vit_main<<<16384 / 2, 64, 0, stream>>>(x, trg, cw1, cb1, cw2, cb2, ws);
    finalize_k<<<1, 64, 0, stream>>>(ws, (float*)d_out);
}